// Round 3
// baseline (2416.396 us; speedup 1.0000x reference)
//
#include <hip/hip_runtime.h>
#include <hip/hip_bf16.h>

#define NB 8
#define NS 4096
#define ND 256
#define NH 8
#define NDK 32
#define NBS (NB*NS)                       // 32768 rows
static const size_t PBUF = (size_t)NB*(NS+1)*ND;   // 8,390,656 floats per big buffer

// ---------------- block reduce helpers (blockDim.x == 256) ----------------
__device__ __forceinline__ float bsum256(float v){
  __shared__ float tmp[4];
  #pragma unroll
  for (int o=32;o>0;o>>=1) v += __shfl_down(v,o);
  if ((threadIdx.x & 63)==0) tmp[threadIdx.x>>6] = v;
  __syncthreads();
  float r = tmp[0]+tmp[1]+tmp[2]+tmp[3];
  __syncthreads();
  return r;
}
__device__ __forceinline__ float bmax256(float v){
  __shared__ float tmp[4];
  #pragma unroll
  for (int o=32;o>0;o>>=1) v = fmaxf(v, __shfl_down(v,o));
  if ((threadIdx.x & 63)==0) tmp[threadIdx.x>>6] = v;
  __syncthreads();
  float r = fmaxf(fmaxf(tmp[0],tmp[1]),fmaxf(tmp[2],tmp[3]));
  __syncthreads();
  return r;
}

// ---------------- dead-simple GEMM: one block per row of A[M,256] @ W[256,256] ----------------
// remap 0: Y row = row
// remap 1: input row r=(b*4096+t) -> output row b*4097+1+t  (relay k/v bulk)
// remap 2: output row = row*4097                            (relay k/v row 0 from s)
__global__ __launch_bounds__(256) void rowgemm(const float* __restrict__ A,
    const float* __restrict__ W, float* __restrict__ Y, int remap)
{
  const int row = blockIdx.x;
  const int j = threadIdx.x;
  __shared__ float a[ND];
  a[j] = A[(size_t)row*ND + j];
  __syncthreads();
  float acc = 0.f;
  #pragma unroll 8
  for (int d=0; d<ND; d++)
    acc = fmaf(a[d], W[(size_t)d*ND + j], acc);
  size_t orow = (size_t)row;
  if (remap == 1)      orow = (size_t)(row>>12)*(NS+1) + 1 + (row&4095);
  else if (remap == 2) orow = (size_t)row*(NS+1);
  Y[orow*ND + j] = acc;
}

// ---------------- satellite attention: one block per position ----------------
// Context order (matches ref): 0=left(h[t-1] or 0), 1=self, 2=right(h[t+1] or 0), 3=entity, 4=relay-s
__global__ __launch_bounds__(256) void sat_attn2(const float* __restrict__ Q,
    const float* __restrict__ KH, const float* __restrict__ VH,
    const float* __restrict__ KE, const float* __restrict__ VE,
    const float* __restrict__ KS, const float* __restrict__ VS,
    float* __restrict__ O)
{
  const int pos = blockIdx.x;           // 0..NBS-1
  const int b = pos >> 12, t = pos & 4095;
  const int j = threadIdx.x;            // 0..255 = h*32 + dv
  __shared__ float q[ND];
  __shared__ float k[5][ND];
  __shared__ float v[5][ND];
  __shared__ float sc[5][NH];

  q[j]    = Q[(size_t)pos*ND + j];
  k[1][j] = KH[(size_t)pos*ND + j];
  v[1][j] = VH[(size_t)pos*ND + j];
  k[0][j] = (t > 0)      ? KH[(size_t)(pos-1)*ND + j] : 0.f;   // zero-pad token -> k=0
  v[0][j] = (t > 0)      ? VH[(size_t)(pos-1)*ND + j] : 0.f;
  k[2][j] = (t < NS-1)   ? KH[(size_t)(pos+1)*ND + j] : 0.f;
  v[2][j] = (t < NS-1)   ? VH[(size_t)(pos+1)*ND + j] : 0.f;
  k[3][j] = KE[(size_t)pos*ND + j];
  v[3][j] = VE[(size_t)pos*ND + j];
  k[4][j] = KS[(size_t)b*ND + j];
  v[4][j] = VS[(size_t)b*ND + j];
  __syncthreads();

  if (j < 40){
    int c = j >> 3, hh = j & 7;
    float acc = 0.f;
    #pragma unroll
    for (int i=0;i<NDK;i++) acc = fmaf(q[hh*NDK+i], k[c][hh*NDK+i], acc);
    sc[c][hh] = acc * 0.17677669529663687f;     // 1/sqrt(32); zero-k context -> exactly 0
  }
  __syncthreads();

  const int h = j >> 5;
  float s0=sc[0][h], s1=sc[1][h], s2=sc[2][h], s3=sc[3][h], s4=sc[4][h];
  float m = fmaxf(fmaxf(fmaxf(s0,s1),fmaxf(s2,s3)),s4);
  float p0=expf(s0-m), p1=expf(s1-m), p2=expf(s2-m), p3=expf(s3-m), p4=expf(s4-m);
  float inv = 1.0f/(p0+p1+p2+p3+p4);
  float o = p0*v[0][j] + p1*v[1][j] + p2*v[2][j] + p3*v[3][j] + p4*v[4][j];
  O[(size_t)pos*ND + j] = o * inv;
}

// ---------------- residual add + LayerNorm -> f32 out ----------------
__global__ __launch_bounds__(256) void add_ln(const float* __restrict__ X,
    const float* __restrict__ R, const float* __restrict__ g, const float* __restrict__ bta,
    float* __restrict__ Y)
{
  int row = blockIdx.x, j = threadIdx.x;
  size_t idx = (size_t)row*ND + j;
  float x = X[idx] + R[idx];
  float mu = bsum256(x) * (1.0f/ND);
  float d = x - mu;
  float var = bsum256(d*d) * (1.0f/ND);
  Y[idx] = d * rsqrtf(var + 1e-6f) * g[j] + bta[j];
}

// ---------------- relay attention: block = (b, head) ----------------
__global__ __launch_bounds__(256) void rel_attn(const float* __restrict__ QR,
    const float* __restrict__ KR, const float* __restrict__ VR, float* __restrict__ ORL)
{
  const int NK = NS+1;
  int b = blockIdx.x >> 3, h = blockIdx.x & 7;
  int tid = threadIdx.x;
  __shared__ float sc[NS+1];
  __shared__ float qs[NDK];
  __shared__ float red[8][NDK];
  if (tid < NDK) qs[tid] = QR[(size_t)b*ND + h*NDK + tid];
  __syncthreads();
  const float scale = 0.17677669529663687f;
  for (int k=tid; k<NK; k+=256){
    const float* kp = KR + ((size_t)b*NK + k)*ND + h*NDK;
    float sdot = 0.f;
    #pragma unroll
    for (int i=0;i<NDK;i++) sdot = fmaf(qs[i], kp[i], sdot);
    sc[k] = sdot * scale;
  }
  __syncthreads();
  float lm = -1e30f;
  for (int k=tid; k<NK; k+=256) lm = fmaxf(lm, sc[k]);
  float m = bmax256(lm);
  float ls = 0.f;
  for (int k=tid; k<NK; k+=256){ float p = expf(sc[k]-m); sc[k] = p; ls += p; }
  float ssum = bsum256(ls);
  float inv = 1.0f/ssum;
  int grp = tid>>5, d = tid&31;
  float acc = 0.f;
  for (int k=grp; k<NK; k+=8)
    acc = fmaf(sc[k], VR[((size_t)b*NK + k)*ND + h*NDK + d], acc);
  red[grp][d] = acc;
  __syncthreads();
  if (grp == 0){
    float tot = 0.f;
    #pragma unroll
    for (int i=0;i<8;i++) tot += red[i][d];
    ORL[(size_t)b*ND + h*NDK + d] = tot * inv;
  }
}

// ---------------- relay output: orl@wo + s -> LN -> f32 tail of out ----------------
__global__ __launch_bounds__(256) void rel_out(const float* __restrict__ ORL,
    const float* __restrict__ WO, const float* __restrict__ Sv,
    const float* __restrict__ g, const float* __restrict__ bta,
    float* __restrict__ out)
{
  int b = blockIdx.x, j = threadIdx.x;
  __shared__ float ol[ND];
  ol[j] = ORL[(size_t)b*ND + j];
  __syncthreads();
  float x = 0.f;
  for (int d=0; d<ND; d++) x = fmaf(ol[d], WO[(size_t)d*ND + j], x);
  x += Sv[(size_t)b*ND + j];
  float mu = bsum256(x) * (1.0f/ND);
  float dd = x - mu;
  float var = bsum256(dd*dd) * (1.0f/ND);
  out[(size_t)NBS*ND + (size_t)b*ND + j] = dd * rsqrtf(var + 1e-6f) * g[j] + bta[j];
}

extern "C" void kernel_launch(void* const* d_in, const int* in_sizes, int n_in,
                              void* d_out, int out_size, void* d_ws, size_t ws_size,
                              hipStream_t stream)
{
  const float* h      = (const float*)d_in[0];
  const float* e      = (const float*)d_in[1];
  const float* s      = (const float*)d_in[2];
  const float* sat_wq = (const float*)d_in[3];
  const float* sat_wk = (const float*)d_in[4];
  const float* sat_wv = (const float*)d_in[5];
  const float* sat_wo = (const float*)d_in[6];
  const float* sat_g  = (const float*)d_in[7];
  const float* sat_b  = (const float*)d_in[8];
  const float* rel_wq = (const float*)d_in[9];
  const float* rel_wk = (const float*)d_in[10];
  const float* rel_wv = (const float*)d_in[11];
  const float* rel_wo = (const float*)d_in[12];
  const float* rel_g  = (const float*)d_in[13];
  const float* rel_b  = (const float*)d_in[14];
  float* out = (float*)d_out;            // f32: reference outputs are float32

  float* ws = (float*)d_ws;
  float* b0 = ws;              // q        -> later oproj out
  float* b1 = ws + PBUF;       // kh
  float* b2 = ws + 2*PBUF;     // vh
  float* b3 = ws + 3*PBUF;     // ke       -> later kr [B,4097,256]
  float* b4 = ws + 4*PBUF;     // ve       -> later vr [B,4097,256]
  float* b5 = ws + 5*PBUF;     // o (satellite attention out)
  float* ks  = ws + 6*PBUF;
  float* vs  = ks + (size_t)NB*ND;
  float* qr  = vs + (size_t)NB*ND;
  float* orl = qr + (size_t)NB*ND;

  // satellite projections
  rowgemm<<<NBS, 256, 0, stream>>>(h, sat_wq, b0, 0);
  rowgemm<<<NBS, 256, 0, stream>>>(h, sat_wk, b1, 0);
  rowgemm<<<NBS, 256, 0, stream>>>(h, sat_wv, b2, 0);
  rowgemm<<<NBS, 256, 0, stream>>>(e, sat_wk, b3, 0);
  rowgemm<<<NBS, 256, 0, stream>>>(e, sat_wv, b4, 0);
  rowgemm<<<NB,  256, 0, stream>>>(s, sat_wk, ks, 0);
  rowgemm<<<NB,  256, 0, stream>>>(s, sat_wv, vs, 0);

  // satellite attention + output projection + LN -> h_out directly into d_out (f32)
  sat_attn2<<<NBS, 256, 0, stream>>>(b0, b1, b2, b3, b4, ks, vs, b5);
  rowgemm<<<NBS, 256, 0, stream>>>(b5, sat_wo, b0, 0);              // oproj into b0
  add_ln<<<NBS, 256, 0, stream>>>(b0, h, sat_g, sat_b, out);        // h_out (f32) at out[0..NBS*ND)

  // relay: q from s; k/v over [s; h_out]
  rowgemm<<<NB,  256, 0, stream>>>(s, rel_wq, qr, 0);
  rowgemm<<<NB,  256, 0, stream>>>(s, rel_wk, b3, 2);               // kr row 0 per batch
  rowgemm<<<NB,  256, 0, stream>>>(s, rel_wv, b4, 2);               // vr row 0 per batch
  rowgemm<<<NBS, 256, 0, stream>>>(out, rel_wk, b3, 1);             // kr rows 1..4096
  rowgemm<<<NBS, 256, 0, stream>>>(out, rel_wv, b4, 1);             // vr rows 1..4096
  rel_attn<<<NB*NH, 256, 0, stream>>>(qr, b3, b4, orl);
  rel_out<<<NB, 256, 0, stream>>>(orl, rel_wo, s, rel_g, rel_b, out);
}

// Round 4
// 495.806 us; speedup vs baseline: 4.8737x; 4.8737x over previous
//
#include <hip/hip_runtime.h>
#include <hip/hip_bf16.h>

typedef unsigned short ushort_t;
typedef unsigned int uint_t;
typedef __attribute__((ext_vector_type(8))) short bf16x8;
typedef __attribute__((ext_vector_type(4))) float f32x4;

#define NB 8
#define NS 4096
#define ND 256
#define NH 8
#define NDK 32
#define NBS (NB*NS)                       // 32768 rows
static const size_t PBUF = (size_t)NB*(NS+1)*ND;   // 8,390,656 floats per big f32 buffer
static const size_t HSZ  = (size_t)NBS*ND;         // 8,388,608 elems (bf16 buffers)

__device__ __forceinline__ ushort_t f2b(float x){
  union { __hip_bfloat16 b; ushort_t u; } cv; cv.b = __float2bfloat16(x); return cv.u;
}

// ---------------- block reduce helpers (blockDim.x == 256) ----------------
__device__ __forceinline__ float bsum256(float v){
  __shared__ float tmp[4];
  #pragma unroll
  for (int o=32;o>0;o>>=1) v += __shfl_down(v,o);
  if ((threadIdx.x & 63)==0) tmp[threadIdx.x>>6] = v;
  __syncthreads();
  float r = tmp[0]+tmp[1]+tmp[2]+tmp[3];
  __syncthreads();
  return r;
}
__device__ __forceinline__ float bmax256(float v){
  __shared__ float tmp[4];
  #pragma unroll
  for (int o=32;o>0;o>>=1) v = fmaxf(v, __shfl_down(v,o));
  if ((threadIdx.x & 63)==0) tmp[threadIdx.x>>6] = v;
  __syncthreads();
  float r = fmaxf(fmaxf(tmp[0],tmp[1]),fmaxf(tmp[2],tmp[3]));
  __syncthreads();
  return r;
}

// ---------------- weight transpose + bf16 cast: W[256k][256n] -> Wt[256n][256k] ----------------
__global__ __launch_bounds__(256) void transp_w(const float* __restrict__ W, ushort_t* __restrict__ Wt)
{
  __shared__ float t[64][68];
  const int k0 = blockIdx.x*64, n0 = blockIdx.y*64;
  const int tr = threadIdx.x>>4, tc4 = (threadIdx.x&15)*4;
  #pragma unroll
  for (int i=0;i<4;i++){
    int r = tr + i*16;
    float4 v = *(const float4*)&W[(size_t)(k0+r)*ND + n0 + tc4];
    t[r][tc4]=v.x; t[r][tc4+1]=v.y; t[r][tc4+2]=v.z; t[r][tc4+3]=v.w;
  }
  __syncthreads();
  #pragma unroll
  for (int i=0;i<4;i++){
    int n = tr + i*16;
    uint_t w0 = f2b(t[tc4+0][n]) | ((uint_t)f2b(t[tc4+1][n])<<16);
    uint_t w1 = f2b(t[tc4+2][n]) | ((uint_t)f2b(t[tc4+3][n])<<16);
    *(uint2*)&Wt[(size_t)(n0+n)*ND + k0 + tc4] = make_uint2(w0,w1);
  }
}

// ---------------- f32 -> bf16 convert (8 elems/thread, exact-sized grid) ----------------
__global__ __launch_bounds__(256) void cvtbf16(const float* __restrict__ X, ushort_t* __restrict__ Y)
{
  size_t i = ((size_t)blockIdx.x*256 + threadIdx.x)*8;
  float4 a = *(const float4*)(X+i), b = *(const float4*)(X+i+4);
  uint4 o;
  o.x = f2b(a.x) | ((uint_t)f2b(a.y)<<16);
  o.y = f2b(a.z) | ((uint_t)f2b(a.w)<<16);
  o.z = f2b(b.x) | ((uint_t)f2b(b.y)<<16);
  o.w = f2b(b.z) | ((uint_t)f2b(b.w)<<16);
  *(uint4*)(Y+i) = o;
}

// ---------------- bf16 MFMA GEMM: A[M,256](bf16) @ Wt[256n][256k](bf16,T) -> Y[M,256](f32) ----------------
// block 256 thr = 4 waves (2x2), tile 128x128, BK=32, acc 4x4 frags of 16x16x32
// remap 1: input row r -> output row (r>>12)*4097 + 1 + (r&4095)
__global__ __launch_bounds__(256) void gemm_bf16(const ushort_t* __restrict__ A,
    const ushort_t* __restrict__ Wt, float* __restrict__ Y, int remap)
{
  __shared__ __align__(16) ushort_t As[128][40];   // +8 pad: 80B row stride
  __shared__ __align__(16) ushort_t Bs[128][40];   // [n][k]
  const int tid  = threadIdx.x;
  const int row0 = blockIdx.x*128;
  const int col0 = blockIdx.y*128;
  const int lane = tid & 63;
  const int wave = tid >> 6;
  const int wr = (wave>>1)*64, wc = (wave&1)*64;
  const int l15 = lane & 15, lg = lane >> 4;       // lg in 0..3
  const int sm = tid>>1;                           // staging row 0..127
  const int sk = (tid&1)*16;                       // staging k offset 0/16

  f32x4 acc[4][4] = {};

  for (int k0=0; k0<ND; k0+=32){
    {
      const ushort_t* srcA = A  + (size_t)(row0+sm)*ND + k0 + sk;
      const ushort_t* srcB = Wt + (size_t)(col0+sm)*ND + k0 + sk;
      *(bf16x8*)&As[sm][sk]   = *(const bf16x8*)(srcA);
      *(bf16x8*)&As[sm][sk+8] = *(const bf16x8*)(srcA+8);
      *(bf16x8*)&Bs[sm][sk]   = *(const bf16x8*)(srcB);
      *(bf16x8*)&Bs[sm][sk+8] = *(const bf16x8*)(srcB+8);
    }
    __syncthreads();
    bf16x8 af[4], bf[4];
    #pragma unroll
    for (int mi=0;mi<4;mi++) af[mi] = *(const bf16x8*)&As[wr+mi*16+l15][lg*8];
    #pragma unroll
    for (int ni=0;ni<4;ni++) bf[ni] = *(const bf16x8*)&Bs[wc+ni*16+l15][lg*8];
    #pragma unroll
    for (int mi=0;mi<4;mi++)
      #pragma unroll
      for (int ni=0;ni<4;ni++)
        acc[mi][ni] = __builtin_amdgcn_mfma_f32_16x16x32_bf16(af[mi], bf[ni], acc[mi][ni], 0,0,0);
    __syncthreads();
  }

  #pragma unroll
  for (int mi=0;mi<4;mi++){
    #pragma unroll
    for (int r=0;r<4;r++){
      int row = row0 + wr + mi*16 + lg*4 + r;      // C/D: row=(lane>>4)*4+reg
      size_t orow = remap ? (size_t)(row>>12)*(NS+1) + 1 + (row&4095) : (size_t)row;
      #pragma unroll
      for (int ni=0;ni<4;ni++)
        Y[orow*ND + col0 + wc + ni*16 + l15] = acc[mi][ni][r];  // col=lane&15
    }
  }
}

// ---------------- dead-simple f32 GEMM for tiny s-projections ----------------
// remap 0: Y row = row ; remap 2: output row = row*4097
__global__ __launch_bounds__(256) void rowgemm(const float* __restrict__ A,
    const float* __restrict__ W, float* __restrict__ Y, int remap)
{
  const int row = blockIdx.x;
  const int j = threadIdx.x;
  __shared__ float a[ND];
  a[j] = A[(size_t)row*ND + j];
  __syncthreads();
  float acc = 0.f;
  #pragma unroll 8
  for (int d=0; d<ND; d++)
    acc = fmaf(a[d], W[(size_t)d*ND + j], acc);
  size_t orow = (size_t)row;
  if (remap == 2) orow = (size_t)row*(NS+1);
  Y[orow*ND + j] = acc;
}

// ---------------- satellite attention: one block per position; bf16 output ----------------
__global__ __launch_bounds__(256) void sat_attn2(const float* __restrict__ Q,
    const float* __restrict__ KH, const float* __restrict__ VH,
    const float* __restrict__ KE, const float* __restrict__ VE,
    const float* __restrict__ KS, const float* __restrict__ VS,
    ushort_t* __restrict__ O)
{
  const int pos = blockIdx.x;
  const int b = pos >> 12, t = pos & 4095;
  const int j = threadIdx.x;
  __shared__ float q[ND];
  __shared__ float k[5][ND];
  __shared__ float v[5][ND];
  __shared__ float sc[5][NH];

  q[j]    = Q[(size_t)pos*ND + j];
  k[1][j] = KH[(size_t)pos*ND + j];
  v[1][j] = VH[(size_t)pos*ND + j];
  k[0][j] = (t > 0)    ? KH[(size_t)(pos-1)*ND + j] : 0.f;
  v[0][j] = (t > 0)    ? VH[(size_t)(pos-1)*ND + j] : 0.f;
  k[2][j] = (t < NS-1) ? KH[(size_t)(pos+1)*ND + j] : 0.f;
  v[2][j] = (t < NS-1) ? VH[(size_t)(pos+1)*ND + j] : 0.f;
  k[3][j] = KE[(size_t)pos*ND + j];
  v[3][j] = VE[(size_t)pos*ND + j];
  k[4][j] = KS[(size_t)b*ND + j];
  v[4][j] = VS[(size_t)b*ND + j];
  __syncthreads();

  if (j < 40){
    int c = j >> 3, hh = j & 7;
    float acc = 0.f;
    #pragma unroll
    for (int i=0;i<NDK;i++) acc = fmaf(q[hh*NDK+i], k[c][hh*NDK+i], acc);
    sc[c][hh] = acc * 0.17677669529663687f;
  }
  __syncthreads();

  const int h = j >> 5;
  float s0=sc[0][h], s1=sc[1][h], s2=sc[2][h], s3=sc[3][h], s4=sc[4][h];
  float m = fmaxf(fmaxf(fmaxf(s0,s1),fmaxf(s2,s3)),s4);
  float p0=expf(s0-m), p1=expf(s1-m), p2=expf(s2-m), p3=expf(s3-m), p4=expf(s4-m);
  float inv = 1.0f/(p0+p1+p2+p3+p4);
  float o = p0*v[0][j] + p1*v[1][j] + p2*v[2][j] + p3*v[3][j] + p4*v[4][j];
  O[(size_t)pos*ND + j] = f2b(o * inv);
}

// ---------------- residual add + LayerNorm -> f32 out + bf16 copy ----------------
__global__ __launch_bounds__(256) void add_ln(const float* __restrict__ X,
    const float* __restrict__ R, const float* __restrict__ g, const float* __restrict__ bta,
    float* __restrict__ Yf, ushort_t* __restrict__ Yb)
{
  int row = blockIdx.x, j = threadIdx.x;
  size_t idx = (size_t)row*ND + j;
  float x = X[idx] + R[idx];
  float mu = bsum256(x) * (1.0f/ND);
  float d = x - mu;
  float var = bsum256(d*d) * (1.0f/ND);
  float y = d * rsqrtf(var + 1e-6f) * g[j] + bta[j];
  Yf[idx] = y;
  Yb[idx] = f2b(y);
}

// ---------------- relay attention: block = (b, head) ----------------
__global__ __launch_bounds__(256) void rel_attn(const float* __restrict__ QR,
    const float* __restrict__ KR, const float* __restrict__ VR, float* __restrict__ ORL)
{
  const int NK = NS+1;
  int b = blockIdx.x >> 3, h = blockIdx.x & 7;
  int tid = threadIdx.x;
  __shared__ float sc[NS+1];
  __shared__ float qs[NDK];
  __shared__ float red[8][NDK];
  if (tid < NDK) qs[tid] = QR[(size_t)b*ND + h*NDK + tid];
  __syncthreads();
  const float scale = 0.17677669529663687f;
  for (int k=tid; k<NK; k+=256){
    const float* kp = KR + ((size_t)b*NK + k)*ND + h*NDK;
    float sdot = 0.f;
    #pragma unroll
    for (int i=0;i<NDK;i++) sdot = fmaf(qs[i], kp[i], sdot);
    sc[k] = sdot * scale;
  }
  __syncthreads();
  float lm = -1e30f;
  for (int k=tid; k<NK; k+=256) lm = fmaxf(lm, sc[k]);
  float m = bmax256(lm);
  float ls = 0.f;
  for (int k=tid; k<NK; k+=256){ float p = expf(sc[k]-m); sc[k] = p; ls += p; }
  float ssum = bsum256(ls);
  float inv = 1.0f/ssum;
  int grp = tid>>5, d = tid&31;
  float acc = 0.f;
  for (int k=grp; k<NK; k+=8)
    acc = fmaf(sc[k], VR[((size_t)b*NK + k)*ND + h*NDK + d], acc);
  red[grp][d] = acc;
  __syncthreads();
  if (grp == 0){
    float tot = 0.f;
    #pragma unroll
    for (int i=0;i<8;i++) tot += red[i][d];
    ORL[(size_t)b*ND + h*NDK + d] = tot * inv;
  }
}

// ---------------- relay output: orl@wo + s -> LN -> f32 tail of out ----------------
__global__ __launch_bounds__(256) void rel_out(const float* __restrict__ ORL,
    const float* __restrict__ WO, const float* __restrict__ Sv,
    const float* __restrict__ g, const float* __restrict__ bta,
    float* __restrict__ out)
{
  int b = blockIdx.x, j = threadIdx.x;
  __shared__ float ol[ND];
  ol[j] = ORL[(size_t)b*ND + j];
  __syncthreads();
  float x = 0.f;
  for (int d=0; d<ND; d++) x = fmaf(ol[d], WO[(size_t)d*ND + j], x);
  x += Sv[(size_t)b*ND + j];
  float mu = bsum256(x) * (1.0f/ND);
  float dd = x - mu;
  float var = bsum256(dd*dd) * (1.0f/ND);
  out[(size_t)NBS*ND + (size_t)b*ND + j] = dd * rsqrtf(var + 1e-6f) * g[j] + bta[j];
}

extern "C" void kernel_launch(void* const* d_in, const int* in_sizes, int n_in,
                              void* d_out, int out_size, void* d_ws, size_t ws_size,
                              hipStream_t stream)
{
  const float* h      = (const float*)d_in[0];
  const float* e      = (const float*)d_in[1];
  const float* s      = (const float*)d_in[2];
  const float* sat_wq = (const float*)d_in[3];
  const float* sat_wk = (const float*)d_in[4];
  const float* sat_wv = (const float*)d_in[5];
  const float* sat_wo = (const float*)d_in[6];
  const float* sat_g  = (const float*)d_in[7];
  const float* sat_b  = (const float*)d_in[8];
  const float* rel_wq = (const float*)d_in[9];
  const float* rel_wk = (const float*)d_in[10];
  const float* rel_wv = (const float*)d_in[11];
  const float* rel_wo = (const float*)d_in[12];
  const float* rel_g  = (const float*)d_in[13];
  const float* rel_b  = (const float*)d_in[14];
  float* out = (float*)d_out;

  float* ws = (float*)d_ws;
  float* b0 = ws;              // q -> later oproj out
  float* b1 = ws + PBUF;       // kh
  float* b2 = ws + 2*PBUF;     // vh
  float* b3 = ws + 3*PBUF;     // ke -> later kr [B,4097,256]
  float* b4 = ws + 4*PBUF;     // ve -> later vr [B,4097,256]
  ushort_t* hb = (ushort_t*)(ws + 5*PBUF);  // h bf16 -> later h_out bf16
  ushort_t* eb = hb + HSZ;                  // e bf16 -> later sat-attn-out bf16
  ushort_t* Wt = eb + HSZ;                  // 6 transposed bf16 weights
  ushort_t* Wtq  = Wt;
  ushort_t* Wtk  = Wt + 1*65536;
  ushort_t* Wtv  = Wt + 2*65536;
  ushort_t* Wto  = Wt + 3*65536;
  ushort_t* Wtrk = Wt + 4*65536;
  ushort_t* Wtrv = Wt + 5*65536;
  float* smalls = (float*)(Wt + 6*65536);
  float* ks  = smalls;
  float* vs  = smalls + 2048;
  float* qr  = smalls + 4096;
  float* orl = smalls + 6144;

  dim3 tgrid(4,4), ggrid(NBS/128, 2), gb(256);

  // prep: transposed bf16 weights + bf16 activations
  transp_w<<<tgrid, gb, 0, stream>>>(sat_wq, Wtq);
  transp_w<<<tgrid, gb, 0, stream>>>(sat_wk, Wtk);
  transp_w<<<tgrid, gb, 0, stream>>>(sat_wv, Wtv);
  transp_w<<<tgrid, gb, 0, stream>>>(sat_wo, Wto);
  transp_w<<<tgrid, gb, 0, stream>>>(rel_wk, Wtrk);
  transp_w<<<tgrid, gb, 0, stream>>>(rel_wv, Wtrv);
  cvtbf16<<<4096, gb, 0, stream>>>(h, hb);
  cvtbf16<<<4096, gb, 0, stream>>>(e, eb);

  // satellite projections (MFMA)
  gemm_bf16<<<ggrid, gb, 0, stream>>>(hb, Wtq, b0, 0);   // q
  gemm_bf16<<<ggrid, gb, 0, stream>>>(hb, Wtk, b1, 0);   // kh
  gemm_bf16<<<ggrid, gb, 0, stream>>>(hb, Wtv, b2, 0);   // vh
  gemm_bf16<<<ggrid, gb, 0, stream>>>(eb, Wtk, b3, 0);   // ke
  gemm_bf16<<<ggrid, gb, 0, stream>>>(eb, Wtv, b4, 0);   // ve
  rowgemm<<<NB, gb, 0, stream>>>(s, sat_wk, ks, 0);
  rowgemm<<<NB, gb, 0, stream>>>(s, sat_wv, vs, 0);

  // satellite attention (writes bf16 into eb) + oproj + LN
  sat_attn2<<<NBS, gb, 0, stream>>>(b0, b1, b2, b3, b4, ks, vs, eb);
  gemm_bf16<<<ggrid, gb, 0, stream>>>(eb, Wto, b0, 0);   // oproj
  add_ln<<<NBS, gb, 0, stream>>>(b0, h, sat_g, sat_b, out, hb);  // h_out: f32 -> out, bf16 -> hb

  // relay: q from s; k/v over [s; h_out]
  rowgemm<<<NB, gb, 0, stream>>>(s, rel_wq, qr, 0);
  rowgemm<<<NB, gb, 0, stream>>>(s, rel_wk, b3, 2);      // kr row 0 per batch
  rowgemm<<<NB, gb, 0, stream>>>(s, rel_wv, b4, 2);      // vr row 0 per batch
  gemm_bf16<<<ggrid, gb, 0, stream>>>(hb, Wtrk, b3, 1);  // kr rows 1..4096
  gemm_bf16<<<ggrid, gb, 0, stream>>>(hb, Wtrv, b4, 1);  // vr rows 1..4096
  rel_attn<<<NB*NH, gb, 0, stream>>>(qr, b3, b4, orl);
  rel_out<<<NB, gb, 0, stream>>>(orl, rel_wo, s, rel_g, rel_b, out);
}

// Round 5
// 364.158 us; speedup vs baseline: 6.6356x; 1.3615x over previous
//
#include <hip/hip_runtime.h>
#include <hip/hip_bf16.h>

typedef unsigned short ushort_t;
typedef unsigned int uint_t;
typedef __attribute__((ext_vector_type(8))) short bf16x8;
typedef __attribute__((ext_vector_type(4))) float f32x4;

#define NB 8
#define NS 4096
#define ND 256
#define NH 8
#define NDK 32
#define NBS (NB*NS)                       // 32768 rows
#define NK  (NS+1)                        // 4097 relay keys
#define CH  513                           // relay split-K chunk
#define NCH 8
static const size_t PBUF = (size_t)NB*(NS+1)*ND;   // 8,390,656 floats per big f32 buffer
static const size_t HSZ  = (size_t)NBS*ND;         // 8,388,608 elems (bf16 buffers)

__device__ __forceinline__ ushort_t f2b(float x){
  union { __hip_bfloat16 b; ushort_t u; } cv; cv.b = __float2bfloat16(x); return cv.u;
}

// ---------------- block reduce helpers (blockDim.x == 256) ----------------
__device__ __forceinline__ float bsum256(float v){
  __shared__ float tmp[4];
  #pragma unroll
  for (int o=32;o>0;o>>=1) v += __shfl_down(v,o);
  if ((threadIdx.x & 63)==0) tmp[threadIdx.x>>6] = v;
  __syncthreads();
  float r = tmp[0]+tmp[1]+tmp[2]+tmp[3];
  __syncthreads();
  return r;
}
__device__ __forceinline__ float bmax256(float v){
  __shared__ float tmp[4];
  #pragma unroll
  for (int o=32;o>0;o>>=1) v = fmaxf(v, __shfl_down(v,o));
  if ((threadIdx.x & 63)==0) tmp[threadIdx.x>>6] = v;
  __syncthreads();
  float r = fmaxf(fmaxf(tmp[0],tmp[1]),fmaxf(tmp[2],tmp[3]));
  __syncthreads();
  return r;
}

// ---------------- weight transpose + bf16 cast: W[256k][256n] -> Wt[256n][256k] ----------------
__global__ __launch_bounds__(256) void transp_w(const float* __restrict__ W, ushort_t* __restrict__ Wt)
{
  __shared__ float t[64][68];
  const int k0 = blockIdx.x*64, n0 = blockIdx.y*64;
  const int tr = threadIdx.x>>4, tc4 = (threadIdx.x&15)*4;
  #pragma unroll
  for (int i=0;i<4;i++){
    int r = tr + i*16;
    float4 v = *(const float4*)&W[(size_t)(k0+r)*ND + n0 + tc4];
    t[r][tc4]=v.x; t[r][tc4+1]=v.y; t[r][tc4+2]=v.z; t[r][tc4+3]=v.w;
  }
  __syncthreads();
  #pragma unroll
  for (int i=0;i<4;i++){
    int n = tr + i*16;
    uint_t w0 = f2b(t[tc4+0][n]) | ((uint_t)f2b(t[tc4+1][n])<<16);
    uint_t w1 = f2b(t[tc4+2][n]) | ((uint_t)f2b(t[tc4+3][n])<<16);
    *(uint2*)&Wt[(size_t)(n0+n)*ND + k0 + tc4] = make_uint2(w0,w1);
  }
}

// ---------------- f32 -> bf16 convert (8 elems/thread) ----------------
__global__ __launch_bounds__(256) void cvtbf16(const float* __restrict__ X, ushort_t* __restrict__ Y)
{
  size_t i = ((size_t)blockIdx.x*256 + threadIdx.x)*8;
  float4 a = *(const float4*)(X+i), b = *(const float4*)(X+i+4);
  uint4 o;
  o.x = f2b(a.x) | ((uint_t)f2b(a.y)<<16);
  o.y = f2b(a.z) | ((uint_t)f2b(a.w)<<16);
  o.z = f2b(b.x) | ((uint_t)f2b(b.y)<<16);
  o.w = f2b(b.z) | ((uint_t)f2b(b.w)<<16);
  *(uint4*)(Y+i) = o;
}

// ---------------- bf16 MFMA GEMM: A[M,256](bf16) @ Wt[256n][256k](bf16,T) -> Y[M,256](f32) ----------------
__global__ __launch_bounds__(256) void gemm_bf16(const ushort_t* __restrict__ A,
    const ushort_t* __restrict__ Wt, float* __restrict__ Y, int remap)
{
  __shared__ __align__(16) ushort_t As[128][40];
  __shared__ __align__(16) ushort_t Bs[128][40];
  const int tid  = threadIdx.x;
  const int row0 = blockIdx.x*128;
  const int col0 = blockIdx.y*128;
  const int lane = tid & 63;
  const int wave = tid >> 6;
  const int wr = (wave>>1)*64, wc = (wave&1)*64;
  const int l15 = lane & 15, lg = lane >> 4;
  const int sm = tid>>1;
  const int sk = (tid&1)*16;

  f32x4 acc[4][4] = {};

  for (int k0=0; k0<ND; k0+=32){
    {
      const ushort_t* srcA = A  + (size_t)(row0+sm)*ND + k0 + sk;
      const ushort_t* srcB = Wt + (size_t)(col0+sm)*ND + k0 + sk;
      *(bf16x8*)&As[sm][sk]   = *(const bf16x8*)(srcA);
      *(bf16x8*)&As[sm][sk+8] = *(const bf16x8*)(srcA+8);
      *(bf16x8*)&Bs[sm][sk]   = *(const bf16x8*)(srcB);
      *(bf16x8*)&Bs[sm][sk+8] = *(const bf16x8*)(srcB+8);
    }
    __syncthreads();
    bf16x8 af[4], bfr[4];
    #pragma unroll
    for (int mi=0;mi<4;mi++) af[mi] = *(const bf16x8*)&As[wr+mi*16+l15][lg*8];
    #pragma unroll
    for (int ni=0;ni<4;ni++) bfr[ni] = *(const bf16x8*)&Bs[wc+ni*16+l15][lg*8];
    #pragma unroll
    for (int mi=0;mi<4;mi++)
      #pragma unroll
      for (int ni=0;ni<4;ni++)
        acc[mi][ni] = __builtin_amdgcn_mfma_f32_16x16x32_bf16(af[mi], bfr[ni], acc[mi][ni], 0,0,0);
    __syncthreads();
  }

  #pragma unroll
  for (int mi=0;mi<4;mi++){
    #pragma unroll
    for (int r=0;r<4;r++){
      int row = row0 + wr + mi*16 + lg*4 + r;
      size_t orow = remap ? (size_t)(row>>12)*(NS+1) + 1 + (row&4095) : (size_t)row;
      #pragma unroll
      for (int ni=0;ni<4;ni++)
        Y[orow*ND + col0 + wc + ni*16 + l15] = acc[mi][ni][r];
    }
  }
}

// ---------------- dead-simple f32 GEMM for tiny s-projections ----------------
__global__ __launch_bounds__(256) void rowgemm(const float* __restrict__ A,
    const float* __restrict__ W, float* __restrict__ Y, int remap)
{
  const int row = blockIdx.x;
  const int j = threadIdx.x;
  __shared__ float a[ND];
  a[j] = A[(size_t)row*ND + j];
  __syncthreads();
  float acc = 0.f;
  #pragma unroll 8
  for (int d=0; d<ND; d++)
    acc = fmaf(a[d], W[(size_t)d*ND + j], acc);
  size_t orow = (size_t)row;
  if (remap == 2) orow = (size_t)row*(NS+1);
  Y[orow*ND + j] = acc;
}

// ---------------- satellite attention: one block per position; bf16 output ----------------
__global__ __launch_bounds__(256) void sat_attn2(const float* __restrict__ Q,
    const float* __restrict__ KH, const float* __restrict__ VH,
    const float* __restrict__ KE, const float* __restrict__ VE,
    const float* __restrict__ KS, const float* __restrict__ VS,
    ushort_t* __restrict__ O)
{
  const int pos = blockIdx.x;
  const int b = pos >> 12, t = pos & 4095;
  const int j = threadIdx.x;
  __shared__ float q[ND];
  __shared__ float k[5][ND];
  __shared__ float v[5][ND];
  __shared__ float sc[5][NH];

  q[j]    = Q[(size_t)pos*ND + j];
  k[1][j] = KH[(size_t)pos*ND + j];
  v[1][j] = VH[(size_t)pos*ND + j];
  k[0][j] = (t > 0)    ? KH[(size_t)(pos-1)*ND + j] : 0.f;
  v[0][j] = (t > 0)    ? VH[(size_t)(pos-1)*ND + j] : 0.f;
  k[2][j] = (t < NS-1) ? KH[(size_t)(pos+1)*ND + j] : 0.f;
  v[2][j] = (t < NS-1) ? VH[(size_t)(pos+1)*ND + j] : 0.f;
  k[3][j] = KE[(size_t)pos*ND + j];
  v[3][j] = VE[(size_t)pos*ND + j];
  k[4][j] = KS[(size_t)b*ND + j];
  v[4][j] = VS[(size_t)b*ND + j];
  __syncthreads();

  if (j < 40){
    int c = j >> 3, hh = j & 7;
    float acc = 0.f;
    #pragma unroll
    for (int i=0;i<NDK;i++) acc = fmaf(q[hh*NDK+i], k[c][hh*NDK+i], acc);
    sc[c][hh] = acc * 0.17677669529663687f;
  }
  __syncthreads();

  const int h = j >> 5;
  float s0=sc[0][h], s1=sc[1][h], s2=sc[2][h], s3=sc[3][h], s4=sc[4][h];
  float m = fmaxf(fmaxf(fmaxf(s0,s1),fmaxf(s2,s3)),s4);
  float p0=expf(s0-m), p1=expf(s1-m), p2=expf(s2-m), p3=expf(s3-m), p4=expf(s4-m);
  float inv = 1.0f/(p0+p1+p2+p3+p4);
  float o = p0*v[0][j] + p1*v[1][j] + p2*v[2][j] + p3*v[3][j] + p4*v[4][j];
  O[(size_t)pos*ND + j] = f2b(o * inv);
}

// ---------------- residual add + LayerNorm -> f32 out + bf16 copy ----------------
__global__ __launch_bounds__(256) void add_ln(const float* __restrict__ X,
    const float* __restrict__ R, const float* __restrict__ g, const float* __restrict__ bta,
    float* __restrict__ Yf, ushort_t* __restrict__ Yb)
{
  int row = blockIdx.x, j = threadIdx.x;
  size_t idx = (size_t)row*ND + j;
  float x = X[idx] + R[idx];
  float mu = bsum256(x) * (1.0f/ND);
  float d = x - mu;
  float var = bsum256(d*d) * (1.0f/ND);
  float y = d * rsqrtf(var + 1e-6f) * g[j] + bta[j];
  Yf[idx] = y;
  Yb[idx] = f2b(y);
}

// ---------------- relay attention phase 1: split-K partials ----------------
// grid (NB*NH, NCH); partial index p = bh*NCH + c
__global__ __launch_bounds__(256) void rel_part(const float* __restrict__ QR,
    const float* __restrict__ KR, const float* __restrict__ VR,
    float* __restrict__ pO, float* __restrict__ pM, float* __restrict__ pL)
{
  const int bh = blockIdx.x;
  const int b = bh >> 3, h = bh & 7;
  const int c = blockIdx.y;
  const int k0 = c*CH;
  const int kn = min(NK, k0+CH) - k0;
  const int tid = threadIdx.x;
  __shared__ float sc[CH];
  __shared__ float qs[NDK];
  __shared__ float red[8][NDK];
  if (tid < NDK) qs[tid] = QR[(size_t)b*ND + h*NDK + tid];
  __syncthreads();
  const float scale = 0.17677669529663687f;
  for (int kk=tid; kk<kn; kk+=256){
    const float* kp = KR + ((size_t)b*NK + k0 + kk)*ND + h*NDK;
    float sdot = 0.f;
    #pragma unroll
    for (int i=0;i<NDK;i++) sdot = fmaf(qs[i], kp[i], sdot);
    sc[kk] = sdot * scale;
  }
  __syncthreads();
  float lm = -1e30f;
  for (int kk=tid; kk<kn; kk+=256) lm = fmaxf(lm, sc[kk]);
  float m = bmax256(lm);
  float ls = 0.f;
  for (int kk=tid; kk<kn; kk+=256){ float p = expf(sc[kk]-m); sc[kk] = p; ls += p; }
  float lsum = bsum256(ls);
  int grp = tid>>5, d = tid&31;
  float acc = 0.f;
  for (int kk=grp; kk<kn; kk+=8)
    acc = fmaf(sc[kk], VR[((size_t)b*NK + k0 + kk)*ND + h*NDK + d], acc);
  red[grp][d] = acc;
  __syncthreads();
  if (grp == 0){
    float tot = 0.f;
    #pragma unroll
    for (int i=0;i<8;i++) tot += red[i][d];
    pO[((size_t)bh*NCH + c)*NDK + d] = tot;        // unnormalized
    if (d == 0){ pM[bh*NCH + c] = m; pL[bh*NCH + c] = lsum; }
  }
}

// ---------------- relay attention phase 2: online-softmax merge ----------------
// grid NB, 256 thr: thread = h*32+d
__global__ __launch_bounds__(256) void rel_merge(const float* __restrict__ pO,
    const float* __restrict__ pM, const float* __restrict__ pL, float* __restrict__ ORL)
{
  const int b = blockIdx.x;
  const int h = threadIdx.x >> 5, d = threadIdx.x & 31;
  const int bh = b*NH + h;
  float m = -1e30f;
  #pragma unroll
  for (int c=0;c<NCH;c++) m = fmaxf(m, pM[bh*NCH + c]);
  float o = 0.f, l = 0.f;
  #pragma unroll
  for (int c=0;c<NCH;c++){
    float w = expf(pM[bh*NCH + c] - m);
    o = fmaf(pO[((size_t)bh*NCH + c)*NDK + d], w, o);
    l = fmaf(pL[bh*NCH + c], w, l);
  }
  ORL[(size_t)b*ND + h*NDK + d] = o / l;
}

// ---------------- relay output: orl@wo + s -> LN -> f32 tail of out ----------------
__global__ __launch_bounds__(256) void rel_out(const float* __restrict__ ORL,
    const float* __restrict__ WO, const float* __restrict__ Sv,
    const float* __restrict__ g, const float* __restrict__ bta,
    float* __restrict__ out)
{
  int b = blockIdx.x, j = threadIdx.x;
  __shared__ float ol[ND];
  ol[j] = ORL[(size_t)b*ND + j];
  __syncthreads();
  float x = 0.f;
  for (int d=0; d<ND; d++) x = fmaf(ol[d], WO[(size_t)d*ND + j], x);
  x += Sv[(size_t)b*ND + j];
  float mu = bsum256(x) * (1.0f/ND);
  float dd = x - mu;
  float var = bsum256(dd*dd) * (1.0f/ND);
  out[(size_t)NBS*ND + (size_t)b*ND + j] = dd * rsqrtf(var + 1e-6f) * g[j] + bta[j];
}

extern "C" void kernel_launch(void* const* d_in, const int* in_sizes, int n_in,
                              void* d_out, int out_size, void* d_ws, size_t ws_size,
                              hipStream_t stream)
{
  const float* h      = (const float*)d_in[0];
  const float* e      = (const float*)d_in[1];
  const float* s      = (const float*)d_in[2];
  const float* sat_wq = (const float*)d_in[3];
  const float* sat_wk = (const float*)d_in[4];
  const float* sat_wv = (const float*)d_in[5];
  const float* sat_wo = (const float*)d_in[6];
  const float* sat_g  = (const float*)d_in[7];
  const float* sat_b  = (const float*)d_in[8];
  const float* rel_wq = (const float*)d_in[9];
  const float* rel_wk = (const float*)d_in[10];
  const float* rel_wv = (const float*)d_in[11];
  const float* rel_wo = (const float*)d_in[12];
  const float* rel_g  = (const float*)d_in[13];
  const float* rel_b  = (const float*)d_in[14];
  float* out = (float*)d_out;

  float* ws = (float*)d_ws;
  float* b0 = ws;              // q -> later oproj out
  float* b1 = ws + PBUF;       // kh
  float* b2 = ws + 2*PBUF;     // vh
  float* b3 = ws + 3*PBUF;     // ke -> later kr [B,4097,256]
  float* b4 = ws + 4*PBUF;     // ve -> later vr [B,4097,256]
  ushort_t* hb = (ushort_t*)(ws + 5*PBUF);  // h bf16 -> later h_out bf16
  ushort_t* eb = hb + HSZ;                  // e bf16 -> later sat-attn-out bf16
  ushort_t* Wt = eb + HSZ;                  // 6 transposed bf16 weights
  ushort_t* Wtq  = Wt;
  ushort_t* Wtk  = Wt + 1*65536;
  ushort_t* Wtv  = Wt + 2*65536;
  ushort_t* Wto  = Wt + 3*65536;
  ushort_t* Wtrk = Wt + 4*65536;
  ushort_t* Wtrv = Wt + 5*65536;
  float* smalls = (float*)(Wt + 6*65536);
  float* ks  = smalls;
  float* vs  = smalls + 2048;
  float* qr  = smalls + 4096;
  float* orl = smalls + 6144;
  float* pO  = smalls + 8192;                       // [64][8][32]
  float* pM  = pO + (size_t)NB*NH*NCH*NDK;          // [64][8]
  float* pL  = pM + NB*NH*NCH;                      // [64][8]

  dim3 tgrid(4,4), ggrid(NBS/128, 2), gb(256);

  // prep: transposed bf16 weights + bf16 activations
  transp_w<<<tgrid, gb, 0, stream>>>(sat_wq, Wtq);
  transp_w<<<tgrid, gb, 0, stream>>>(sat_wk, Wtk);
  transp_w<<<tgrid, gb, 0, stream>>>(sat_wv, Wtv);
  transp_w<<<tgrid, gb, 0, stream>>>(sat_wo, Wto);
  transp_w<<<tgrid, gb, 0, stream>>>(rel_wk, Wtrk);
  transp_w<<<tgrid, gb, 0, stream>>>(rel_wv, Wtrv);
  cvtbf16<<<4096, gb, 0, stream>>>(h, hb);
  cvtbf16<<<4096, gb, 0, stream>>>(e, eb);

  // satellite projections (MFMA)
  gemm_bf16<<<ggrid, gb, 0, stream>>>(hb, Wtq, b0, 0);   // q
  gemm_bf16<<<ggrid, gb, 0, stream>>>(hb, Wtk, b1, 0);   // kh
  gemm_bf16<<<ggrid, gb, 0, stream>>>(hb, Wtv, b2, 0);   // vh
  gemm_bf16<<<ggrid, gb, 0, stream>>>(eb, Wtk, b3, 0);   // ke
  gemm_bf16<<<ggrid, gb, 0, stream>>>(eb, Wtv, b4, 0);   // ve
  rowgemm<<<NB, gb, 0, stream>>>(s, sat_wk, ks, 0);
  rowgemm<<<NB, gb, 0, stream>>>(s, sat_wv, vs, 0);

  // satellite attention (writes bf16 into eb) + oproj + LN
  sat_attn2<<<NBS, gb, 0, stream>>>(b0, b1, b2, b3, b4, ks, vs, eb);
  gemm_bf16<<<ggrid, gb, 0, stream>>>(eb, Wto, b0, 0);   // oproj
  add_ln<<<NBS, gb, 0, stream>>>(b0, h, sat_g, sat_b, out, hb);  // h_out: f32 -> out, bf16 -> hb

  // relay: q from s; k/v over [s; h_out]
  rowgemm<<<NB, gb, 0, stream>>>(s, rel_wq, qr, 0);
  rowgemm<<<NB, gb, 0, stream>>>(s, rel_wk, b3, 2);      // kr row 0 per batch
  rowgemm<<<NB, gb, 0, stream>>>(s, rel_wv, b4, 2);      // vr row 0 per batch
  gemm_bf16<<<ggrid, gb, 0, stream>>>(hb, Wtrk, b3, 1);  // kr rows 1..4096
  gemm_bf16<<<ggrid, gb, 0, stream>>>(hb, Wtrv, b4, 1);  // vr rows 1..4096
  rel_part<<<dim3(NB*NH, NCH), gb, 0, stream>>>(qr, b3, b4, pO, pM, pL);
  rel_merge<<<NB, gb, 0, stream>>>(pO, pM, pL, orl);
  rel_out<<<NB, gb, 0, stream>>>(orl, rel_wo, s, rel_g, rel_b, out);
}

// Round 6
// 305.445 us; speedup vs baseline: 7.9111x; 1.1922x over previous
//
#include <hip/hip_runtime.h>
#include <hip/hip_bf16.h>

typedef unsigned short ushort_t;
typedef unsigned int uint_t;
typedef __attribute__((ext_vector_type(8))) short bf16x8;
typedef __attribute__((ext_vector_type(4))) float f32x4;

#define NB 8
#define NS 4096
#define ND 256
#define NH 8
#define NDK 32
#define NBS (NB*NS)                       // 32768 rows
#define NK  (NS+1)                        // 4097 relay keys
#define CH  513                           // relay split-K chunk
#define NCH 8
#define SPOS 4                            // positions per sat_attn3 block
static const size_t PBUF = (size_t)NB*(NS+1)*ND;   // 8,390,656 floats per big f32 buffer
static const size_t HSZ  = (size_t)NBS*ND;         // 8,388,608 elems (bf16 buffers)

__device__ __forceinline__ ushort_t f2b(float x){
  union { __hip_bfloat16 b; ushort_t u; } cv; cv.b = __float2bfloat16(x); return cv.u;
}
__device__ __forceinline__ float b2f(ushort_t u){
  union { uint_t u; float f; } cv; cv.u = ((uint_t)u) << 16; return cv.f;
}

// ---------------- block reduce helpers (blockDim.x == 256) ----------------
__device__ __forceinline__ float bsum256(float v){
  __shared__ float tmp[4];
  #pragma unroll
  for (int o=32;o>0;o>>=1) v += __shfl_down(v,o);
  if ((threadIdx.x & 63)==0) tmp[threadIdx.x>>6] = v;
  __syncthreads();
  float r = tmp[0]+tmp[1]+tmp[2]+tmp[3];
  __syncthreads();
  return r;
}
__device__ __forceinline__ float bmax256(float v){
  __shared__ float tmp[4];
  #pragma unroll
  for (int o=32;o>0;o>>=1) v = fmaxf(v, __shfl_down(v,o));
  if ((threadIdx.x & 63)==0) tmp[threadIdx.x>>6] = v;
  __syncthreads();
  float r = fmaxf(fmaxf(tmp[0],tmp[1]),fmaxf(tmp[2],tmp[3]));
  __syncthreads();
  return r;
}

// ---------------- weight transpose + bf16 cast: W[256k][256n] -> Wt[256n][256k] ----------------
__global__ __launch_bounds__(256) void transp_w(const float* __restrict__ W, ushort_t* __restrict__ Wt)
{
  __shared__ float t[64][68];
  const int k0 = blockIdx.x*64, n0 = blockIdx.y*64;
  const int tr = threadIdx.x>>4, tc4 = (threadIdx.x&15)*4;
  #pragma unroll
  for (int i=0;i<4;i++){
    int r = tr + i*16;
    float4 v = *(const float4*)&W[(size_t)(k0+r)*ND + n0 + tc4];
    t[r][tc4]=v.x; t[r][tc4+1]=v.y; t[r][tc4+2]=v.z; t[r][tc4+3]=v.w;
  }
  __syncthreads();
  #pragma unroll
  for (int i=0;i<4;i++){
    int n = tr + i*16;
    uint_t w0 = f2b(t[tc4+0][n]) | ((uint_t)f2b(t[tc4+1][n])<<16);
    uint_t w1 = f2b(t[tc4+2][n]) | ((uint_t)f2b(t[tc4+3][n])<<16);
    *(uint2*)&Wt[(size_t)(n0+n)*ND + k0 + tc4] = make_uint2(w0,w1);
  }
}

// ---------------- f32 -> bf16 convert (8 elems/thread) ----------------
__global__ __launch_bounds__(256) void cvtbf16(const float* __restrict__ X, ushort_t* __restrict__ Y)
{
  size_t i = ((size_t)blockIdx.x*256 + threadIdx.x)*8;
  float4 a = *(const float4*)(X+i), b = *(const float4*)(X+i+4);
  uint4 o;
  o.x = f2b(a.x) | ((uint_t)f2b(a.y)<<16);
  o.y = f2b(a.z) | ((uint_t)f2b(a.w)<<16);
  o.z = f2b(b.x) | ((uint_t)f2b(b.y)<<16);
  o.w = f2b(b.z) | ((uint_t)f2b(b.w)<<16);
  *(uint4*)(Y+i) = o;
}

// ---------------- bf16 MFMA GEMM: A[M,256](bf16) @ Wt[256n][256k](bf16,T) ----------------
// OBF16=1 -> bf16 output, else f32. remap 1: row r -> (r>>12)*4097 + 1 + (r&4095)
template<int OBF16>
__global__ __launch_bounds__(256) void gemm_t(const ushort_t* __restrict__ A,
    const ushort_t* __restrict__ Wt, void* __restrict__ Yv, int remap)
{
  __shared__ __align__(16) ushort_t As[128][40];
  __shared__ __align__(16) ushort_t Bs[128][40];
  const int tid  = threadIdx.x;
  const int row0 = blockIdx.x*128;
  const int col0 = blockIdx.y*128;
  const int lane = tid & 63;
  const int wave = tid >> 6;
  const int wr = (wave>>1)*64, wc = (wave&1)*64;
  const int l15 = lane & 15, lg = lane >> 4;
  const int sm = tid>>1;
  const int sk = (tid&1)*16;

  f32x4 acc[4][4] = {};

  for (int k0=0; k0<ND; k0+=32){
    {
      const ushort_t* srcA = A  + (size_t)(row0+sm)*ND + k0 + sk;
      const ushort_t* srcB = Wt + (size_t)(col0+sm)*ND + k0 + sk;
      *(bf16x8*)&As[sm][sk]   = *(const bf16x8*)(srcA);
      *(bf16x8*)&As[sm][sk+8] = *(const bf16x8*)(srcA+8);
      *(bf16x8*)&Bs[sm][sk]   = *(const bf16x8*)(srcB);
      *(bf16x8*)&Bs[sm][sk+8] = *(const bf16x8*)(srcB+8);
    }
    __syncthreads();
    bf16x8 af[4], bfr[4];
    #pragma unroll
    for (int mi=0;mi<4;mi++) af[mi] = *(const bf16x8*)&As[wr+mi*16+l15][lg*8];
    #pragma unroll
    for (int ni=0;ni<4;ni++) bfr[ni] = *(const bf16x8*)&Bs[wc+ni*16+l15][lg*8];
    #pragma unroll
    for (int mi=0;mi<4;mi++)
      #pragma unroll
      for (int ni=0;ni<4;ni++)
        acc[mi][ni] = __builtin_amdgcn_mfma_f32_16x16x32_bf16(af[mi], bfr[ni], acc[mi][ni], 0,0,0);
    __syncthreads();
  }

  #pragma unroll
  for (int mi=0;mi<4;mi++){
    #pragma unroll
    for (int r=0;r<4;r++){
      int row = row0 + wr + mi*16 + lg*4 + r;
      size_t orow = remap ? (size_t)(row>>12)*(NS+1) + 1 + (row&4095) : (size_t)row;
      #pragma unroll
      for (int ni=0;ni<4;ni++){
        if (OBF16) ((ushort_t*)Yv)[orow*ND + col0 + wc + ni*16 + l15] = f2b(acc[mi][ni][r]);
        else       ((float*)Yv)[orow*ND + col0 + wc + ni*16 + l15]   = acc[mi][ni][r];
      }
    }
  }
}

// ---------------- tiny f32 row-GEMM (s projections, f32 out) ----------------
__global__ __launch_bounds__(256) void rowgemm(const float* __restrict__ A,
    const float* __restrict__ W, float* __restrict__ Y)
{
  const int row = blockIdx.x;
  const int j = threadIdx.x;
  __shared__ float a[ND];
  a[j] = A[(size_t)row*ND + j];
  __syncthreads();
  float acc = 0.f;
  #pragma unroll 8
  for (int d=0; d<ND; d++)
    acc = fmaf(a[d], W[(size_t)d*ND + j], acc);
  Y[(size_t)row*ND + j] = acc;
}

// ---------------- tiny f32 row-GEMM, bf16 out; remap 2: orow = row*4097 ----------------
__global__ __launch_bounds__(256) void rowgemm_b16(const float* __restrict__ A,
    const float* __restrict__ W, ushort_t* __restrict__ Y, int remap)
{
  const int row = blockIdx.x;
  const int j = threadIdx.x;
  __shared__ float a[ND];
  a[j] = A[(size_t)row*ND + j];
  __syncthreads();
  float acc = 0.f;
  #pragma unroll 8
  for (int d=0; d<ND; d++)
    acc = fmaf(a[d], W[(size_t)d*ND + j], acc);
  size_t orow = (remap == 2) ? (size_t)row*(NS+1) : (size_t)row;
  Y[orow*ND + j] = f2b(acc);
}

// ---------------- satellite attention v3: LDS-free, bf16 in/out ----------------
// thread j = h*32+d; each 32-lane group = one (pos, head); SPOS positions per block
__global__ __launch_bounds__(256) void sat_attn3(const ushort_t* __restrict__ Q,
    const ushort_t* __restrict__ KH, const ushort_t* __restrict__ VH,
    const ushort_t* __restrict__ KE, const ushort_t* __restrict__ VE,
    const ushort_t* __restrict__ KS, const ushort_t* __restrict__ VS,
    ushort_t* __restrict__ O)
{
  const int j = threadIdx.x;
  const int pos0 = blockIdx.x * SPOS;      // SPOS divides 4096 -> whole block same batch
  const int b = pos0 >> 12;
  const float scale = 0.17677669529663687f;
  const float ks = b2f(KS[(size_t)b*ND + j]);
  const float vs = b2f(VS[(size_t)b*ND + j]);
  #pragma unroll
  for (int pi=0; pi<SPOS; ++pi){
    const int pos = pos0 + pi;
    const int t = pos & 4095;
    const size_t base = (size_t)pos*ND + j;
    float q  = b2f(Q[base]);
    float k0 = (t > 0)    ? b2f(KH[base-ND]) : 0.f;   // zero-pad token: k=0 -> score exactly 0
    float k1 = b2f(KH[base]);
    float k2 = (t < NS-1) ? b2f(KH[base+ND]) : 0.f;
    float k3 = b2f(KE[base]);
    float s0=q*k0, s1=q*k1, s2=q*k2, s3=q*k3, s4=q*ks;
    #pragma unroll
    for (int mm=1; mm<32; mm<<=1){
      s0 += __shfl_xor(s0,mm); s1 += __shfl_xor(s1,mm); s2 += __shfl_xor(s2,mm);
      s3 += __shfl_xor(s3,mm); s4 += __shfl_xor(s4,mm);
    }
    s0*=scale; s1*=scale; s2*=scale; s3*=scale; s4*=scale;
    float m = fmaxf(fmaxf(fmaxf(s0,s1),fmaxf(s2,s3)),s4);
    float p0=expf(s0-m), p1=expf(s1-m), p2=expf(s2-m), p3=expf(s3-m), p4=expf(s4-m);
    float inv = 1.0f/(p0+p1+p2+p3+p4);
    float v0 = (t > 0)    ? b2f(VH[base-ND]) : 0.f;
    float v1 = b2f(VH[base]);
    float v2 = (t < NS-1) ? b2f(VH[base+ND]) : 0.f;
    float v3 = b2f(VE[base]);
    float o = (p0*v0 + p1*v1 + p2*v2 + p3*v3 + p4*vs) * inv;
    O[base] = f2b(o);
  }
}

// ---------------- residual add + LayerNorm -> f32 out + bf16 copy ----------------
__global__ __launch_bounds__(256) void add_ln(const float* __restrict__ X,
    const float* __restrict__ R, const float* __restrict__ g, const float* __restrict__ bta,
    float* __restrict__ Yf, ushort_t* __restrict__ Yb)
{
  int row = blockIdx.x, j = threadIdx.x;
  size_t idx = (size_t)row*ND + j;
  float x = X[idx] + R[idx];
  float mu = bsum256(x) * (1.0f/ND);
  float d = x - mu;
  float var = bsum256(d*d) * (1.0f/ND);
  float y = d * rsqrtf(var + 1e-6f) * g[j] + bta[j];
  Yf[idx] = y;
  Yb[idx] = f2b(y);
}

// ---------------- relay attention phase 1: split-K partials, bf16 K/V ----------------
__global__ __launch_bounds__(256) void rel_part(const float* __restrict__ QR,
    const ushort_t* __restrict__ KR, const ushort_t* __restrict__ VR,
    float* __restrict__ pO, float* __restrict__ pM, float* __restrict__ pL)
{
  const int bh = blockIdx.x;
  const int b = bh >> 3, h = bh & 7;
  const int c = blockIdx.y;
  const int k0 = c*CH;
  const int kn = min(NK, k0+CH) - k0;
  const int tid = threadIdx.x;
  __shared__ float sc[CH];
  __shared__ float qs[NDK];
  __shared__ float red[8][NDK];
  if (tid < NDK) qs[tid] = QR[(size_t)b*ND + h*NDK + tid];
  __syncthreads();
  const float scale = 0.17677669529663687f;
  for (int kk=tid; kk<kn; kk+=256){
    const ushort_t* kp = KR + ((size_t)b*NK + k0 + kk)*ND + h*NDK;
    float sdot = 0.f;
    #pragma unroll
    for (int w=0; w<4; w++){
      bf16x8 kv = *(const bf16x8*)(kp + w*8);
      #pragma unroll
      for (int i=0;i<8;i++) sdot = fmaf(qs[w*8+i], b2f((ushort_t)kv[i]), sdot);
    }
    sc[kk] = sdot * scale;
  }
  __syncthreads();
  float lm = -1e30f;
  for (int kk=tid; kk<kn; kk+=256) lm = fmaxf(lm, sc[kk]);
  float m = bmax256(lm);
  float ls = 0.f;
  for (int kk=tid; kk<kn; kk+=256){ float p = expf(sc[kk]-m); sc[kk] = p; ls += p; }
  float lsum = bsum256(ls);
  int grp = tid>>5, d = tid&31;
  float acc = 0.f;
  for (int kk=grp; kk<kn; kk+=8)
    acc = fmaf(sc[kk], b2f(VR[((size_t)b*NK + k0 + kk)*ND + h*NDK + d]), acc);
  red[grp][d] = acc;
  __syncthreads();
  if (grp == 0){
    float tot = 0.f;
    #pragma unroll
    for (int i=0;i<8;i++) tot += red[i][d];
    pO[((size_t)bh*NCH + c)*NDK + d] = tot;        // unnormalized
    if (d == 0){ pM[bh*NCH + c] = m; pL[bh*NCH + c] = lsum; }
  }
}

// ---------------- relay attention phase 2: online-softmax merge ----------------
__global__ __launch_bounds__(256) void rel_merge(const float* __restrict__ pO,
    const float* __restrict__ pM, const float* __restrict__ pL, float* __restrict__ ORL)
{
  const int b = blockIdx.x;
  const int h = threadIdx.x >> 5, d = threadIdx.x & 31;
  const int bh = b*NH + h;
  float m = -1e30f;
  #pragma unroll
  for (int c=0;c<NCH;c++) m = fmaxf(m, pM[bh*NCH + c]);
  float o = 0.f, l = 0.f;
  #pragma unroll
  for (int c=0;c<NCH;c++){
    float w = expf(pM[bh*NCH + c] - m);
    o = fmaf(pO[((size_t)bh*NCH + c)*NDK + d], w, o);
    l = fmaf(pL[bh*NCH + c], w, l);
  }
  ORL[(size_t)b*ND + h*NDK + d] = o / l;
}

// ---------------- relay output: orl@wo + s -> LN -> f32 tail of out ----------------
__global__ __launch_bounds__(256) void rel_out(const float* __restrict__ ORL,
    const float* __restrict__ WO, const float* __restrict__ Sv,
    const float* __restrict__ g, const float* __restrict__ bta,
    float* __restrict__ out)
{
  int b = blockIdx.x, j = threadIdx.x;
  __shared__ float ol[ND];
  ol[j] = ORL[(size_t)b*ND + j];
  __syncthreads();
  float x = 0.f;
  for (int d=0; d<ND; d++) x = fmaf(ol[d], WO[(size_t)d*ND + j], x);
  x += Sv[(size_t)b*ND + j];
  float mu = bsum256(x) * (1.0f/ND);
  float dd = x - mu;
  float var = bsum256(dd*dd) * (1.0f/ND);
  out[(size_t)NBS*ND + (size_t)b*ND + j] = dd * rsqrtf(var + 1e-6f) * g[j] + bta[j];
}

extern "C" void kernel_launch(void* const* d_in, const int* in_sizes, int n_in,
                              void* d_out, int out_size, void* d_ws, size_t ws_size,
                              hipStream_t stream)
{
  const float* h      = (const float*)d_in[0];
  const float* e      = (const float*)d_in[1];
  const float* s      = (const float*)d_in[2];
  const float* sat_wq = (const float*)d_in[3];
  const float* sat_wk = (const float*)d_in[4];
  const float* sat_wv = (const float*)d_in[5];
  const float* sat_wo = (const float*)d_in[6];
  const float* sat_g  = (const float*)d_in[7];
  const float* sat_b  = (const float*)d_in[8];
  const float* rel_wq = (const float*)d_in[9];
  const float* rel_wk = (const float*)d_in[10];
  const float* rel_wv = (const float*)d_in[11];
  const float* rel_wo = (const float*)d_in[12];
  const float* rel_g  = (const float*)d_in[13];
  const float* rel_b  = (const float*)d_in[14];
  float* out = (float*)d_out;

  float* ws = (float*)d_ws;
  float* b0 = ws;              // q(bf16) -> later oproj out (f32)
  float* b1 = ws + PBUF;       // kh(bf16)
  float* b2 = ws + 2*PBUF;     // vh(bf16)
  float* b3 = ws + 3*PBUF;     // ke(bf16) -> later kr(bf16) [B,4097,256]
  float* b4 = ws + 4*PBUF;     // ve(bf16) -> later vr(bf16) [B,4097,256]
  ushort_t* qb  = (ushort_t*)b0;
  ushort_t* khb = (ushort_t*)b1;
  ushort_t* vhb = (ushort_t*)b2;
  ushort_t* keb = (ushort_t*)b3;
  ushort_t* veb = (ushort_t*)b4;
  ushort_t* krb = (ushort_t*)b3;
  ushort_t* vrb = (ushort_t*)b4;
  ushort_t* hb = (ushort_t*)(ws + 5*PBUF);  // h bf16 -> later h_out bf16
  ushort_t* eb = hb + HSZ;                  // e bf16 -> later sat-attn-out bf16
  ushort_t* Wt = eb + HSZ;                  // 6 transposed bf16 weights
  ushort_t* Wtq  = Wt;
  ushort_t* Wtk  = Wt + 1*65536;
  ushort_t* Wtv  = Wt + 2*65536;
  ushort_t* Wto  = Wt + 3*65536;
  ushort_t* Wtrk = Wt + 4*65536;
  ushort_t* Wtrv = Wt + 5*65536;
  float* smalls = (float*)(Wt + 6*65536);
  ushort_t* ksb = (ushort_t*)smalls;        // 2048 bf16
  ushort_t* vsb = ksb + 2048;
  float* qr  = smalls + 4096;
  float* orl = smalls + 6144;
  float* pO  = smalls + 8192;               // [64][8][32]
  float* pM  = pO + (size_t)NB*NH*NCH*NDK;  // [64][8]
  float* pL  = pM + NB*NH*NCH;              // [64][8]

  dim3 tgrid(4,4), ggrid(NBS/128, 2), gb(256);

  // prep: transposed bf16 weights + bf16 activations
  transp_w<<<tgrid, gb, 0, stream>>>(sat_wq, Wtq);
  transp_w<<<tgrid, gb, 0, stream>>>(sat_wk, Wtk);
  transp_w<<<tgrid, gb, 0, stream>>>(sat_wv, Wtv);
  transp_w<<<tgrid, gb, 0, stream>>>(sat_wo, Wto);
  transp_w<<<tgrid, gb, 0, stream>>>(rel_wk, Wtrk);
  transp_w<<<tgrid, gb, 0, stream>>>(rel_wv, Wtrv);
  cvtbf16<<<4096, gb, 0, stream>>>(h, hb);
  cvtbf16<<<4096, gb, 0, stream>>>(e, eb);

  // satellite projections (MFMA, bf16 out)
  gemm_t<1><<<ggrid, gb, 0, stream>>>(hb, Wtq, qb,  0);
  gemm_t<1><<<ggrid, gb, 0, stream>>>(hb, Wtk, khb, 0);
  gemm_t<1><<<ggrid, gb, 0, stream>>>(hb, Wtv, vhb, 0);
  gemm_t<1><<<ggrid, gb, 0, stream>>>(eb, Wtk, keb, 0);
  gemm_t<1><<<ggrid, gb, 0, stream>>>(eb, Wtv, veb, 0);
  rowgemm_b16<<<NB, gb, 0, stream>>>(s, sat_wk, ksb, 0);
  rowgemm_b16<<<NB, gb, 0, stream>>>(s, sat_wv, vsb, 0);

  // satellite attention (bf16 in, bf16 out into eb) + oproj + LN
  sat_attn3<<<NBS/SPOS, gb, 0, stream>>>(qb, khb, vhb, keb, veb, ksb, vsb, eb);
  gemm_t<0><<<ggrid, gb, 0, stream>>>(eb, Wto, b0, 0);            // oproj f32
  add_ln<<<NBS, gb, 0, stream>>>(b0, h, sat_g, sat_b, out, hb);   // h_out: f32 -> out, bf16 -> hb

  // relay: q from s; k/v over [s; h_out] (bf16)
  rowgemm<<<NB, gb, 0, stream>>>(s, rel_wq, qr);
  rowgemm_b16<<<NB, gb, 0, stream>>>(s, rel_wk, krb, 2);          // kr row 0 per batch
  rowgemm_b16<<<NB, gb, 0, stream>>>(s, rel_wv, vrb, 2);          // vr row 0 per batch
  gemm_t<1><<<ggrid, gb, 0, stream>>>(hb, Wtrk, krb, 1);          // kr rows 1..4096
  gemm_t<1><<<ggrid, gb, 0, stream>>>(hb, Wtrv, vrb, 1);          // vr rows 1..4096
  rel_part<<<dim3(NB*NH, NCH), gb, 0, stream>>>(qr, krb, vrb, pO, pM, pL);
  rel_merge<<<NB, gb, 0, stream>>>(pO, pM, pL, orl);
  rel_out<<<NB, gb, 0, stream>>>(orl, rel_wo, s, rel_g, rel_b, out);
}

// Round 8
// 279.144 us; speedup vs baseline: 8.6565x; 1.0942x over previous
//
#include <hip/hip_runtime.h>
#include <hip/hip_bf16.h>

typedef unsigned short ushort_t;
typedef unsigned int uint_t;
typedef __attribute__((ext_vector_type(8))) short bf16x8;
typedef __attribute__((ext_vector_type(4))) float f32x4;

#define NB 8
#define NS 4096
#define ND 256
#define NH 8
#define NDK 32
#define NBS (NB*NS)                       // 32768 rows
#define NK  (NS+1)                        // 4097 relay keys
#define CH  513                           // relay split-K chunk
#define NCH 8
static const size_t PBUF = (size_t)NB*(NS+1)*ND;   // 8,390,656 floats per big f32 buffer
static const size_t HSZ  = (size_t)NBS*ND;         // 8,388,608 elems (bf16 buffers)

__device__ __forceinline__ ushort_t f2b(float x){
  union { __hip_bfloat16 b; ushort_t u; } cv; cv.b = __float2bfloat16(x); return cv.u;
}
__device__ __forceinline__ float b2f(ushort_t u){
  union { uint_t u; float f; } cv; cv.u = ((uint_t)u) << 16; return cv.f;
}

// ---------------- block reduce helpers (blockDim.x == 256) ----------------
__device__ __forceinline__ float bsum256(float v){
  __shared__ float tmp[4];
  #pragma unroll
  for (int o=32;o>0;o>>=1) v += __shfl_down(v,o);
  if ((threadIdx.x & 63)==0) tmp[threadIdx.x>>6] = v;
  __syncthreads();
  float r = tmp[0]+tmp[1]+tmp[2]+tmp[3];
  __syncthreads();
  return r;
}
__device__ __forceinline__ float bmax256(float v){
  __shared__ float tmp[4];
  #pragma unroll
  for (int o=32;o>0;o>>=1) v = fmaxf(v, __shfl_down(v,o));
  if ((threadIdx.x & 63)==0) tmp[threadIdx.x>>6] = v;
  __syncthreads();
  float r = fmaxf(fmaxf(tmp[0],tmp[1]),fmaxf(tmp[2],tmp[3]));
  __syncthreads();
  return r;
}

// ---------------- weight transpose + bf16 cast: W[256k][256n] -> Wt[256n][256k] ----------------
__global__ __launch_bounds__(256) void transp_w(const float* __restrict__ W, ushort_t* __restrict__ Wt)
{
  __shared__ float t[64][68];
  const int k0 = blockIdx.x*64, n0 = blockIdx.y*64;
  const int tr = threadIdx.x>>4, tc4 = (threadIdx.x&15)*4;
  #pragma unroll
  for (int i=0;i<4;i++){
    int r = tr + i*16;
    float4 v = *(const float4*)&W[(size_t)(k0+r)*ND + n0 + tc4];
    t[r][tc4]=v.x; t[r][tc4+1]=v.y; t[r][tc4+2]=v.z; t[r][tc4+3]=v.w;
  }
  __syncthreads();
  #pragma unroll
  for (int i=0;i<4;i++){
    int n = tr + i*16;
    uint_t w0 = f2b(t[tc4+0][n]) | ((uint_t)f2b(t[tc4+1][n])<<16);
    uint_t w1 = f2b(t[tc4+2][n]) | ((uint_t)f2b(t[tc4+3][n])<<16);
    *(uint2*)&Wt[(size_t)(n0+n)*ND + k0 + tc4] = make_uint2(w0,w1);
  }
}

// ---------------- bf16 MFMA GEMM: A[M,256] @ Wt[ldn rows][256k](bf16,T) -> Y[M,ldn] ----------------
// AF32: A is f32 (converted during staging), else bf16. OBF16: bf16 output, else f32.
// remap 1: output row r -> (r>>12)*4097 + 1 + (r&4095)
template<int AF32, int OBF16>
__global__ __launch_bounds__(256) void gemm_t(const void* __restrict__ Av,
    const ushort_t* __restrict__ Wt, void* __restrict__ Yv, int ldn, int remap)
{
  __shared__ __align__(16) ushort_t As[128][40];
  __shared__ __align__(16) ushort_t Bs[128][40];
  const int tid  = threadIdx.x;
  const int row0 = blockIdx.x*128;
  const int col0 = blockIdx.y*128;
  const int lane = tid & 63;
  const int wave = tid >> 6;
  const int wr = (wave>>1)*64, wc = (wave&1)*64;
  const int l15 = lane & 15, lg = lane >> 4;
  const int sm = tid>>1;
  const int sk = (tid&1)*16;

  f32x4 acc[4][4] = {};

  for (int k0=0; k0<ND; k0+=32){
    if (AF32){
      const float* srcA = (const float*)Av + (size_t)(row0+sm)*ND + k0 + sk;
      float4 a0=*(const float4*)srcA,     a1=*(const float4*)(srcA+4);
      float4 a2=*(const float4*)(srcA+8), a3=*(const float4*)(srcA+12);
      uint4 p0, p1;
      p0.x = f2b(a0.x)|((uint_t)f2b(a0.y)<<16); p0.y = f2b(a0.z)|((uint_t)f2b(a0.w)<<16);
      p0.z = f2b(a1.x)|((uint_t)f2b(a1.y)<<16); p0.w = f2b(a1.z)|((uint_t)f2b(a1.w)<<16);
      p1.x = f2b(a2.x)|((uint_t)f2b(a2.y)<<16); p1.y = f2b(a2.z)|((uint_t)f2b(a2.w)<<16);
      p1.z = f2b(a3.x)|((uint_t)f2b(a3.y)<<16); p1.w = f2b(a3.z)|((uint_t)f2b(a3.w)<<16);
      *(uint4*)&As[sm][sk]   = p0;
      *(uint4*)&As[sm][sk+8] = p1;
    } else {
      const ushort_t* srcA = (const ushort_t*)Av + (size_t)(row0+sm)*ND + k0 + sk;
      *(bf16x8*)&As[sm][sk]   = *(const bf16x8*)(srcA);
      *(bf16x8*)&As[sm][sk+8] = *(const bf16x8*)(srcA+8);
    }
    {
      const ushort_t* srcB = Wt + (size_t)(col0+sm)*ND + k0 + sk;
      *(bf16x8*)&Bs[sm][sk]   = *(const bf16x8*)(srcB);
      *(bf16x8*)&Bs[sm][sk+8] = *(const bf16x8*)(srcB+8);
    }
    __syncthreads();
    bf16x8 af[4], bfr[4];
    #pragma unroll
    for (int mi=0;mi<4;mi++) af[mi] = *(const bf16x8*)&As[wr+mi*16+l15][lg*8];
    #pragma unroll
    for (int ni=0;ni<4;ni++) bfr[ni] = *(const bf16x8*)&Bs[wc+ni*16+l15][lg*8];
    #pragma unroll
    for (int mi=0;mi<4;mi++)
      #pragma unroll
      for (int ni=0;ni<4;ni++)
        acc[mi][ni] = __builtin_amdgcn_mfma_f32_16x16x32_bf16(af[mi], bfr[ni], acc[mi][ni], 0,0,0);
    __syncthreads();
  }

  #pragma unroll
  for (int mi=0;mi<4;mi++){
    #pragma unroll
    for (int r=0;r<4;r++){
      int row = row0 + wr + mi*16 + lg*4 + r;
      size_t orow = remap ? (size_t)(row>>12)*(NS+1) + 1 + (row&4095) : (size_t)row;
      #pragma unroll
      for (int ni=0;ni<4;ni++){
        size_t idx = orow*(size_t)ldn + col0 + wc + ni*16 + l15;
        if (OBF16) ((ushort_t*)Yv)[idx] = f2b(acc[mi][ni][r]);
        else       ((float*)Yv)[idx]    = acc[mi][ni][r];
      }
    }
  }
}

// ---------------- tiny f32 row-GEMM (s projections, f32 out) ----------------
__global__ __launch_bounds__(256) void rowgemm(const float* __restrict__ A,
    const float* __restrict__ W, float* __restrict__ Y)
{
  const int row = blockIdx.x;
  const int j = threadIdx.x;
  __shared__ float a[ND];
  a[j] = A[(size_t)row*ND + j];
  __syncthreads();
  float acc = 0.f;
  #pragma unroll 8
  for (int d=0; d<ND; d++)
    acc = fmaf(a[d], W[(size_t)d*ND + j], acc);
  Y[(size_t)row*ND + j] = acc;
}

// ---------------- tiny f32 row-GEMM, bf16 out, strided/offset; remap2: orow=row*4097 ----------------
__global__ __launch_bounds__(256) void rowgemm_b16(const float* __restrict__ A,
    const float* __restrict__ W, ushort_t* __restrict__ Y, int ldn, int coloff, int remap)
{
  const int row = blockIdx.x;
  const int j = threadIdx.x;
  __shared__ float a[ND];
  a[j] = A[(size_t)row*ND + j];
  __syncthreads();
  float acc = 0.f;
  #pragma unroll 8
  for (int d=0; d<ND; d++)
    acc = fmaf(a[d], W[(size_t)d*ND + j], acc);
  size_t orow = (remap == 2) ? (size_t)row*(NS+1) : (size_t)row;
  Y[orow*(size_t)ldn + coloff + j] = f2b(acc);
}

// ---------------- satellite attention v4: 4-lane groups, bf16x8 vector loads ----------------
// HQ: [M][768] = q|kh|vh fused; EKV: [M][512] = ke|ve fused. 8 positions per block.
__device__ __forceinline__ void load8(float* d, const ushort_t* p){
  bf16x8 v = *(const bf16x8*)p;
  #pragma unroll
  for (int i=0;i<8;i++) d[i] = b2f((ushort_t)v[i]);
}
__device__ __forceinline__ void zero8(float* d){
  #pragma unroll
  for (int i=0;i<8;i++) d[i] = 0.f;
}
__global__ __launch_bounds__(256) void sat_attn4(const ushort_t* __restrict__ HQ,
    const ushort_t* __restrict__ EKV,
    const ushort_t* __restrict__ KS, const ushort_t* __restrict__ VS,
    ushort_t* __restrict__ O)
{
  const int tid = threadIdx.x;
  const int l  = tid & 3;                 // k-slice lane (8 channels each)
  const int g  = tid >> 2;                // group 0..63
  const int hh = g & 7;                   // head
  const int pi = g >> 3;                  // 0..7
  const int pos = blockIdx.x*8 + pi;
  const int b = pos >> 12, t = pos & 4095;
  const int co = hh*NDK + l*8;
  const float scale = 0.17677669529663687f;

  const size_t rq = (size_t)pos*768;
  const size_t re = (size_t)pos*512;
  float q[8], k0[8], k1[8], k2[8], k3[8], k4[8];
  load8(q,  HQ + rq + co);
  load8(k1, HQ + rq + 256 + co);
  load8(k3, EKV + re + co);
  load8(k4, KS + (size_t)b*ND + co);
  if (t > 0)    load8(k0, HQ + rq - 768 + 256 + co);
  else          zero8(k0);
  if (t < NS-1) load8(k2, HQ + rq + 768 + 256 + co);
  else          zero8(k2);

  float s0=0.f,s1=0.f,s2=0.f,s3=0.f,s4=0.f;
  #pragma unroll
  for (int i=0;i<8;i++){
    s0 = fmaf(q[i],k0[i],s0); s1 = fmaf(q[i],k1[i],s1); s2 = fmaf(q[i],k2[i],s2);
    s3 = fmaf(q[i],k3[i],s3); s4 = fmaf(q[i],k4[i],s4);
  }
  #pragma unroll
  for (int mm=1; mm<4; mm<<=1){
    s0 += __shfl_xor(s0,mm); s1 += __shfl_xor(s1,mm); s2 += __shfl_xor(s2,mm);
    s3 += __shfl_xor(s3,mm); s4 += __shfl_xor(s4,mm);
  }
  s0*=scale; s1*=scale; s2*=scale; s3*=scale; s4*=scale;
  float m = fmaxf(fmaxf(fmaxf(s0,s1),fmaxf(s2,s3)),s4);
  float p0=expf(s0-m), p1=expf(s1-m), p2=expf(s2-m), p3=expf(s3-m), p4=expf(s4-m);
  float inv = 1.0f/(p0+p1+p2+p3+p4);

  float v0[8], v1[8], v2[8], v3[8], v4[8];
  load8(v1, HQ + rq + 512 + co);
  load8(v3, EKV + re + 256 + co);
  load8(v4, VS + (size_t)b*ND + co);
  if (t > 0)    load8(v0, HQ + rq - 768 + 512 + co);
  else          zero8(v0);
  if (t < NS-1) load8(v2, HQ + rq + 768 + 512 + co);
  else          zero8(v2);

  float o[8];
  #pragma unroll
  for (int i=0;i<8;i++)
    o[i] = (p0*v0[i] + p1*v1[i] + p2*v2[i] + p3*v3[i] + p4*v4[i]) * inv;
  uint4 pk;
  pk.x = f2b(o[0])|((uint_t)f2b(o[1])<<16);
  pk.y = f2b(o[2])|((uint_t)f2b(o[3])<<16);
  pk.z = f2b(o[4])|((uint_t)f2b(o[5])<<16);
  pk.w = f2b(o[6])|((uint_t)f2b(o[7])<<16);
  *(uint4*)&O[(size_t)pos*ND + co] = pk;
}

// ---------------- residual add + LayerNorm -> f32 out + bf16 copy ----------------
__global__ __launch_bounds__(256) void add_ln(const float* __restrict__ X,
    const float* __restrict__ R, const float* __restrict__ g, const float* __restrict__ bta,
    float* __restrict__ Yf, ushort_t* __restrict__ Yb)
{
  int row = blockIdx.x, j = threadIdx.x;
  size_t idx = (size_t)row*ND + j;
  float x = X[idx] + R[idx];
  float mu = bsum256(x) * (1.0f/ND);
  float d = x - mu;
  float var = bsum256(d*d) * (1.0f/ND);
  float y = d * rsqrtf(var + 1e-6f) * g[j] + bta[j];
  Yf[idx] = y;
  Yb[idx] = f2b(y);
}

// ---------------- relay attention phase 1: split-K partials, fused kr|vr bf16 [B][4097][512] ----------------
__global__ __launch_bounds__(256) void rel_part(const float* __restrict__ QR,
    const ushort_t* __restrict__ KRV,
    float* __restrict__ pO, float* __restrict__ pM, float* __restrict__ pL)
{
  const int bh = blockIdx.x;
  const int b = bh >> 3, h = bh & 7;
  const int c = blockIdx.y;
  const int k0 = c*CH;
  const int kn = min(NK, k0+CH) - k0;
  const int tid = threadIdx.x;
  __shared__ float sc[CH];
  __shared__ float qs[NDK];
  __shared__ float red[8][NDK];
  if (tid < NDK) qs[tid] = QR[(size_t)b*ND + h*NDK + tid];
  __syncthreads();
  const float scale = 0.17677669529663687f;
  for (int kk=tid; kk<kn; kk+=256){
    const ushort_t* kp = KRV + ((size_t)b*NK + k0 + kk)*512 + h*NDK;
    float sdot = 0.f;
    #pragma unroll
    for (int w=0; w<4; w++){
      bf16x8 kv = *(const bf16x8*)(kp + w*8);
      #pragma unroll
      for (int i=0;i<8;i++) sdot = fmaf(qs[w*8+i], b2f((ushort_t)kv[i]), sdot);
    }
    sc[kk] = sdot * scale;
  }
  __syncthreads();
  float lm = -1e30f;
  for (int kk=tid; kk<kn; kk+=256) lm = fmaxf(lm, sc[kk]);
  float m = bmax256(lm);
  float ls = 0.f;
  for (int kk=tid; kk<kn; kk+=256){ float p = expf(sc[kk]-m); sc[kk] = p; ls += p; }
  float lsum = bsum256(ls);
  int grp = tid>>5, d = tid&31;
  float acc = 0.f;
  for (int kk=grp; kk<kn; kk+=8)
    acc = fmaf(sc[kk], b2f(KRV[((size_t)b*NK + k0 + kk)*512 + 256 + h*NDK + d]), acc);
  red[grp][d] = acc;
  __syncthreads();
  if (grp == 0){
    float tot = 0.f;
    #pragma unroll
    for (int i=0;i<8;i++) tot += red[i][d];
    pO[((size_t)bh*NCH + c)*NDK + d] = tot;        // unnormalized
    if (d == 0){ pM[bh*NCH + c] = m; pL[bh*NCH + c] = lsum; }
  }
}

// ---------------- relay attention phase 2: online-softmax merge ----------------
__global__ __launch_bounds__(256) void rel_merge(const float* __restrict__ pO,
    const float* __restrict__ pM, const float* __restrict__ pL, float* __restrict__ ORL)
{
  const int b = blockIdx.x;
  const int h = threadIdx.x >> 5, d = threadIdx.x & 31;
  const int bh = b*NH + h;
  float m = -1e30f;
  #pragma unroll
  for (int c=0;c<NCH;c++) m = fmaxf(m, pM[bh*NCH + c]);
  float o = 0.f, l = 0.f;
  #pragma unroll
  for (int c=0;c<NCH;c++){
    float w = expf(pM[bh*NCH + c] - m);
    o = fmaf(pO[((size_t)bh*NCH + c)*NDK + d], w, o);
    l = fmaf(pL[bh*NCH + c], w, l);
  }
  ORL[(size_t)b*ND + h*NDK + d] = o / l;
}

// ---------------- relay output: orl@wo + s -> LN -> f32 tail of out ----------------
__global__ __launch_bounds__(256) void rel_out(const float* __restrict__ ORL,
    const float* __restrict__ WO, const float* __restrict__ Sv,
    const float* __restrict__ g, const float* __restrict__ bta,
    float* __restrict__ out)
{
  int b = blockIdx.x, j = threadIdx.x;
  __shared__ float ol[ND];
  ol[j] = ORL[(size_t)b*ND + j];
  __syncthreads();
  float x = 0.f;
  for (int d=0; d<ND; d++) x = fmaf(ol[d], WO[(size_t)d*ND + j], x);
  x += Sv[(size_t)b*ND + j];
  float mu = bsum256(x) * (1.0f/ND);
  float dd = x - mu;
  float var = bsum256(dd*dd) * (1.0f/ND);
  out[(size_t)NBS*ND + (size_t)b*ND + j] = dd * rsqrtf(var + 1e-6f) * g[j] + bta[j];
}

extern "C" void kernel_launch(void* const* d_in, const int* in_sizes, int n_in,
                              void* d_out, int out_size, void* d_ws, size_t ws_size,
                              hipStream_t stream)
{
  const float* h      = (const float*)d_in[0];
  const float* e      = (const float*)d_in[1];
  const float* s      = (const float*)d_in[2];
  const float* sat_wq = (const float*)d_in[3];
  const float* sat_wk = (const float*)d_in[4];
  const float* sat_wv = (const float*)d_in[5];
  const float* sat_wo = (const float*)d_in[6];
  const float* sat_g  = (const float*)d_in[7];
  const float* sat_b  = (const float*)d_in[8];
  const float* rel_wq = (const float*)d_in[9];
  const float* rel_wk = (const float*)d_in[10];
  const float* rel_wv = (const float*)d_in[11];
  const float* rel_wo = (const float*)d_in[12];
  const float* rel_g  = (const float*)d_in[13];
  const float* rel_b  = (const float*)d_in[14];
  float* out = (float*)d_out;

  float* ws = (float*)d_ws;
  // layout:
  //   [0 .. 1.5 PBUF)  hQKV bf16 [32768][768] (q|kh|vh)
  //   [2PBUF .. 3PBUF) eKV  bf16 [32768][512] (ke|ve)
  //   [3PBUF .. 4PBUF) oproj out f32 [32768][256]
  //   [4PBUF .. 5PBUF) krv  bf16 [8][4097][512] (kr|vr)
  //   [5PBUF ..)       hb bf16, satO bf16, Wt, smalls
  ushort_t* hQKV = (ushort_t*)ws;
  ushort_t* eKV  = (ushort_t*)(ws + 2*PBUF);
  float*    oprj = ws + 3*PBUF;
  ushort_t* krv  = (ushort_t*)(ws + 4*PBUF);
  ushort_t* hb   = (ushort_t*)(ws + 5*PBUF);   // h_out bf16
  ushort_t* satO = hb + HSZ;                   // satellite attention out bf16
  ushort_t* Wt   = satO + HSZ;                 // 6 transposed bf16 weights (q,k,v,o,rk,rv)
  float* smalls  = (float*)(Wt + 6*65536);
  ushort_t* ksb = (ushort_t*)smalls;           // 2048 bf16
  ushort_t* vsb = ksb + 2048;
  float* qr  = smalls + 4096;
  float* orl = smalls + 6144;
  float* pO  = smalls + 8192;                  // [64][8][32]
  float* pM  = pO + (size_t)NB*NH*NCH*NDK;     // [64][8]
  float* pL  = pM + NB*NH*NCH;                 // [64][8]

  dim3 tgrid(4,4), gb(256);

  // transposed bf16 weights, contiguous: q,k,v,o,rk,rv
  transp_w<<<tgrid, gb, 0, stream>>>(sat_wq, Wt);
  transp_w<<<tgrid, gb, 0, stream>>>(sat_wk, Wt + 1*65536);
  transp_w<<<tgrid, gb, 0, stream>>>(sat_wv, Wt + 2*65536);
  transp_w<<<tgrid, gb, 0, stream>>>(sat_wo, Wt + 3*65536);
  transp_w<<<tgrid, gb, 0, stream>>>(rel_wk, Wt + 4*65536);
  transp_w<<<tgrid, gb, 0, stream>>>(rel_wv, Wt + 5*65536);

  // fused projections (f32 A, converted in staging)
  gemm_t<1,1><<<dim3(NBS/128, 6), gb, 0, stream>>>(h, Wt,           hQKV, 768, 0); // q|kh|vh
  gemm_t<1,1><<<dim3(NBS/128, 4), gb, 0, stream>>>(e, Wt + 1*65536, eKV,  512, 0); // ke|ve
  rowgemm_b16<<<NB, gb, 0, stream>>>(s, sat_wk, ksb, 256, 0, 0);
  rowgemm_b16<<<NB, gb, 0, stream>>>(s, sat_wv, vsb, 256, 0, 0);

  // satellite attention + oproj + LN
  sat_attn4<<<NBS/8, gb, 0, stream>>>(hQKV, eKV, ksb, vsb, satO);
  gemm_t<0,0><<<dim3(NBS/128, 2), gb, 0, stream>>>(satO, Wt + 3*65536, oprj, 256, 0);
  add_ln<<<NBS, gb, 0, stream>>>(oprj, h, sat_g, sat_b, out, hb);  // f32 -> out, bf16 -> hb

  // relay: q from s; fused kr|vr over [s; h_out]
  rowgemm<<<NB, gb, 0, stream>>>(s, rel_wq, qr);
  rowgemm_b16<<<NB, gb, 0, stream>>>(s, rel_wk, krv, 512, 0,   2); // row 0 kr
  rowgemm_b16<<<NB, gb, 0, stream>>>(s, rel_wv, krv, 512, 256, 2); // row 0 vr
  gemm_t<0,1><<<dim3(NBS/128, 4), gb, 0, stream>>>(hb, Wt + 4*65536, krv, 512, 1);
  rel_part<<<dim3(NB*NH, NCH), gb, 0, stream>>>(qr, krv, pO, pM, pL);
  rel_merge<<<NB, gb, 0, stream>>>(pO, pM, pL, orl);
  rel_out<<<NB, gb, 0, stream>>>(orl, rel_wo, s, rel_g, rel_b, out);
}

// Round 9
// 275.719 us; speedup vs baseline: 8.7640x; 1.0124x over previous
//
#include <hip/hip_runtime.h>
#include <hip/hip_bf16.h>

typedef unsigned short ushort_t;
typedef unsigned int uint_t;
typedef __attribute__((ext_vector_type(8))) short bf16x8;
typedef __attribute__((ext_vector_type(4))) float f32x4;

#define NB 8
#define NS 4096
#define ND 256
#define NH 8
#define NDK 32
#define NBS (NB*NS)                       // 32768 rows
#define NK  (NS+1)                        // 4097 relay keys
#define CH  513                           // relay split-K chunk
#define NCH 8
static const size_t PBUF = (size_t)NB*(NS+1)*ND;   // 8,390,656 floats per big f32 buffer
static const size_t HSZ  = (size_t)NBS*ND;         // 8,388,608 elems (bf16 buffers)

__device__ __forceinline__ ushort_t f2b(float x){
  union { __hip_bfloat16 b; ushort_t u; } cv; cv.b = __float2bfloat16(x); return cv.u;
}
__device__ __forceinline__ float b2f(ushort_t u){
  union { uint_t u; float f; } cv; cv.u = ((uint_t)u) << 16; return cv.f;
}

// async global->LDS, 16B per lane, wave-uniform LDS base + lane*16
__device__ __forceinline__ void gload16(const ushort_t* g, ushort_t* l){
  __builtin_amdgcn_global_load_lds(
      (const __attribute__((address_space(1))) void*)g,
      (__attribute__((address_space(3))) void*)l, 16, 0, 0);
}

// ---------------- block reduce helpers (blockDim.x == 256) ----------------
__device__ __forceinline__ float bsum256(float v){
  __shared__ float tmp[4];
  #pragma unroll
  for (int o=32;o>0;o>>=1) v += __shfl_down(v,o);
  if ((threadIdx.x & 63)==0) tmp[threadIdx.x>>6] = v;
  __syncthreads();
  float r = tmp[0]+tmp[1]+tmp[2]+tmp[3];
  __syncthreads();
  return r;
}
__device__ __forceinline__ float bmax256(float v){
  __shared__ float tmp[4];
  #pragma unroll
  for (int o=32;o>0;o>>=1) v = fmaxf(v, __shfl_down(v,o));
  if ((threadIdx.x & 63)==0) tmp[threadIdx.x>>6] = v;
  __syncthreads();
  float r = fmaxf(fmaxf(tmp[0],tmp[1]),fmaxf(tmp[2],tmp[3]));
  __syncthreads();
  return r;
}

// ---------------- weight transpose + bf16 cast: W[256k][256n] -> Wt[256n][256k] ----------------
__global__ __launch_bounds__(256) void transp_w(const float* __restrict__ W, ushort_t* __restrict__ Wt)
{
  __shared__ float t[64][68];
  const int k0 = blockIdx.x*64, n0 = blockIdx.y*64;
  const int tr = threadIdx.x>>4, tc4 = (threadIdx.x&15)*4;
  #pragma unroll
  for (int i=0;i<4;i++){
    int r = tr + i*16;
    float4 v = *(const float4*)&W[(size_t)(k0+r)*ND + n0 + tc4];
    t[r][tc4]=v.x; t[r][tc4+1]=v.y; t[r][tc4+2]=v.z; t[r][tc4+3]=v.w;
  }
  __syncthreads();
  #pragma unroll
  for (int i=0;i<4;i++){
    int n = tr + i*16;
    uint_t w0 = f2b(t[tc4+0][n]) | ((uint_t)f2b(t[tc4+1][n])<<16);
    uint_t w1 = f2b(t[tc4+2][n]) | ((uint_t)f2b(t[tc4+3][n])<<16);
    *(uint2*)&Wt[(size_t)(n0+n)*ND + k0 + tc4] = make_uint2(w0,w1);
  }
}

// ---------------- f32 -> bf16 convert (8 elems/thread) ----------------
__global__ __launch_bounds__(256) void cvtbf16(const float* __restrict__ X, ushort_t* __restrict__ Y)
{
  size_t i = ((size_t)blockIdx.x*256 + threadIdx.x)*8;
  float4 a = *(const float4*)(X+i), b = *(const float4*)(X+i+4);
  uint4 o;
  o.x = f2b(a.x) | ((uint_t)f2b(a.y)<<16);
  o.y = f2b(a.z) | ((uint_t)f2b(a.w)<<16);
  o.z = f2b(b.x) | ((uint_t)f2b(b.y)<<16);
  o.w = f2b(b.z) | ((uint_t)f2b(b.w)<<16);
  *(uint4*)(Y+i) = o;
}

// ---------------- bf16 MFMA GEMM, global_load_lds + double-buffer, 1 barrier/K-step ------------
// A[M,256] bf16 @ Wt[ldn][256] bf16(T) -> Y[M,ldn]. OBF16: bf16 out else f32.
// remap 1: output row r -> (r>>12)*4097 + 1 + (r&4095)
template<int OBF16>
__global__ __launch_bounds__(256) void gemm_lds(const ushort_t* __restrict__ A,
    const ushort_t* __restrict__ Wt, void* __restrict__ Yv, int ldn, int remap)
{
  __shared__ __align__(16) ushort_t As[2][128][32];
  __shared__ __align__(16) ushort_t Bs[2][128][32];
  const int tid  = threadIdx.x;
  const int row0 = blockIdx.x*128;
  const int col0 = blockIdx.y*128;
  const int lane = tid & 63;
  const int wave = tid >> 6;
  const int wr = (wave>>1)*64, wc = (wave&1)*64;
  const int l15 = lane & 15, lg = lane >> 4;
  const int lr = lane >> 2;          // row within 16-row chunk
  const int lc = (lane & 3) * 8;     // bf16 col offset within 32

  const ushort_t* Abase = A  + (size_t)(row0 + wave*32 + lr)*ND + lc;
  const ushort_t* Bbase = Wt + (size_t)(col0 + wave*32 + lr)*ND + lc;

  f32x4 acc[4][4] = {};

  #define STAGE(kt, b) do{ \
    const ushort_t* ga = Abase + (kt)*32; \
    const ushort_t* gw = Bbase + (kt)*32; \
    gload16(ga,          &As[b][wave*32][0]); \
    gload16(ga + 16*ND,  &As[b][wave*32+16][0]); \
    gload16(gw,          &Bs[b][wave*32][0]); \
    gload16(gw + 16*ND,  &Bs[b][wave*32+16][0]); \
  }while(0)

  #define COMPUTE(b) do{ \
    bf16x8 af[4], bfr[4]; \
    _Pragma("unroll") \
    for (int mi=0;mi<4;mi++) af[mi] = *(const bf16x8*)&As[b][wr+mi*16+l15][lg*8]; \
    _Pragma("unroll") \
    for (int ni=0;ni<4;ni++) bfr[ni] = *(const bf16x8*)&Bs[b][wc+ni*16+l15][lg*8]; \
    _Pragma("unroll") \
    for (int mi=0;mi<4;mi++) \
      _Pragma("unroll") \
      for (int ni=0;ni<4;ni++) \
        acc[mi][ni] = __builtin_amdgcn_mfma_f32_16x16x32_bf16(af[mi], bfr[ni], acc[mi][ni], 0,0,0); \
  }while(0)

  STAGE(0, 0);
  __syncthreads();                 // drains vmcnt -> tile 0 resident
  int buf = 0;
  #pragma unroll
  for (int t=0; t<7; ++t){
    STAGE(t+1, buf^1);             // prefetch next tile (async, other buffer)
    COMPUTE(buf);                  // MFMA on current tile (lgkmcnt auto-inserted)
    __syncthreads();               // drains vmcnt+lgkm; next tile ready, buf reusable
    buf ^= 1;
  }
  COMPUTE(buf);                    // last tile, no prefetch
  #undef STAGE
  #undef COMPUTE

  #pragma unroll
  for (int mi=0;mi<4;mi++){
    #pragma unroll
    for (int r=0;r<4;r++){
      int row = row0 + wr + mi*16 + lg*4 + r;
      size_t orow = remap ? (size_t)(row>>12)*(NS+1) + 1 + (row&4095) : (size_t)row;
      #pragma unroll
      for (int ni=0;ni<4;ni++){
        size_t idx = orow*(size_t)ldn + col0 + wc + ni*16 + l15;
        if (OBF16) ((ushort_t*)Yv)[idx] = f2b(acc[mi][ni][r]);
        else       ((float*)Yv)[idx]    = acc[mi][ni][r];
      }
    }
  }
}

// ---------------- tiny f32 row-GEMM (s projections, f32 out) ----------------
__global__ __launch_bounds__(256) void rowgemm(const float* __restrict__ A,
    const float* __restrict__ W, float* __restrict__ Y)
{
  const int row = blockIdx.x;
  const int j = threadIdx.x;
  __shared__ float a[ND];
  a[j] = A[(size_t)row*ND + j];
  __syncthreads();
  float acc = 0.f;
  #pragma unroll 8
  for (int d=0; d<ND; d++)
    acc = fmaf(a[d], W[(size_t)d*ND + j], acc);
  Y[(size_t)row*ND + j] = acc;
}

// ---------------- tiny f32 row-GEMM, bf16 out, strided/offset; remap2: orow=row*4097 ----------------
__global__ __launch_bounds__(256) void rowgemm_b16(const float* __restrict__ A,
    const float* __restrict__ W, ushort_t* __restrict__ Y, int ldn, int coloff, int remap)
{
  const int row = blockIdx.x;
  const int j = threadIdx.x;
  __shared__ float a[ND];
  a[j] = A[(size_t)row*ND + j];
  __syncthreads();
  float acc = 0.f;
  #pragma unroll 8
  for (int d=0; d<ND; d++)
    acc = fmaf(a[d], W[(size_t)d*ND + j], acc);
  size_t orow = (remap == 2) ? (size_t)row*(NS+1) : (size_t)row;
  Y[orow*(size_t)ldn + coloff + j] = f2b(acc);
}

// ---------------- satellite attention v4: 4-lane groups, bf16x8 vector loads ----------------
__device__ __forceinline__ void load8(float* d, const ushort_t* p){
  bf16x8 v = *(const bf16x8*)p;
  #pragma unroll
  for (int i=0;i<8;i++) d[i] = b2f((ushort_t)v[i]);
}
__device__ __forceinline__ void zero8(float* d){
  #pragma unroll
  for (int i=0;i<8;i++) d[i] = 0.f;
}
__global__ __launch_bounds__(256) void sat_attn4(const ushort_t* __restrict__ HQ,
    const ushort_t* __restrict__ EKV,
    const ushort_t* __restrict__ KS, const ushort_t* __restrict__ VS,
    ushort_t* __restrict__ O)
{
  const int tid = threadIdx.x;
  const int l  = tid & 3;
  const int g  = tid >> 2;
  const int hh = g & 7;
  const int pi = g >> 3;
  const int pos = blockIdx.x*8 + pi;
  const int b = pos >> 12, t = pos & 4095;
  const int co = hh*NDK + l*8;
  const float scale = 0.17677669529663687f;

  const size_t rq = (size_t)pos*768;
  const size_t re = (size_t)pos*512;
  float q[8], k0[8], k1[8], k2[8], k3[8], k4[8];
  load8(q,  HQ + rq + co);
  load8(k1, HQ + rq + 256 + co);
  load8(k3, EKV + re + co);
  load8(k4, KS + (size_t)b*ND + co);
  if (t > 0)    load8(k0, HQ + rq - 768 + 256 + co);
  else          zero8(k0);
  if (t < NS-1) load8(k2, HQ + rq + 768 + 256 + co);
  else          zero8(k2);

  float s0=0.f,s1=0.f,s2=0.f,s3=0.f,s4=0.f;
  #pragma unroll
  for (int i=0;i<8;i++){
    s0 = fmaf(q[i],k0[i],s0); s1 = fmaf(q[i],k1[i],s1); s2 = fmaf(q[i],k2[i],s2);
    s3 = fmaf(q[i],k3[i],s3); s4 = fmaf(q[i],k4[i],s4);
  }
  #pragma unroll
  for (int mm=1; mm<4; mm<<=1){
    s0 += __shfl_xor(s0,mm); s1 += __shfl_xor(s1,mm); s2 += __shfl_xor(s2,mm);
    s3 += __shfl_xor(s3,mm); s4 += __shfl_xor(s4,mm);
  }
  s0*=scale; s1*=scale; s2*=scale; s3*=scale; s4*=scale;
  float m = fmaxf(fmaxf(fmaxf(s0,s1),fmaxf(s2,s3)),s4);
  float p0=expf(s0-m), p1=expf(s1-m), p2=expf(s2-m), p3=expf(s3-m), p4=expf(s4-m);
  float inv = 1.0f/(p0+p1+p2+p3+p4);

  float v0[8], v1[8], v2[8], v3[8], v4[8];
  load8(v1, HQ + rq + 512 + co);
  load8(v3, EKV + re + 256 + co);
  load8(v4, VS + (size_t)b*ND + co);
  if (t > 0)    load8(v0, HQ + rq - 768 + 512 + co);
  else          zero8(v0);
  if (t < NS-1) load8(v2, HQ + rq + 768 + 512 + co);
  else          zero8(v2);

  float o[8];
  #pragma unroll
  for (int i=0;i<8;i++)
    o[i] = (p0*v0[i] + p1*v1[i] + p2*v2[i] + p3*v3[i] + p4*v4[i]) * inv;
  uint4 pk;
  pk.x = f2b(o[0])|((uint_t)f2b(o[1])<<16);
  pk.y = f2b(o[2])|((uint_t)f2b(o[3])<<16);
  pk.z = f2b(o[4])|((uint_t)f2b(o[5])<<16);
  pk.w = f2b(o[6])|((uint_t)f2b(o[7])<<16);
  *(uint4*)&O[(size_t)pos*ND + co] = pk;
}

// ---------------- residual add + LayerNorm -> f32 out + bf16 copy ----------------
__global__ __launch_bounds__(256) void add_ln(const float* __restrict__ X,
    const float* __restrict__ R, const float* __restrict__ g, const float* __restrict__ bta,
    float* __restrict__ Yf, ushort_t* __restrict__ Yb)
{
  int row = blockIdx.x, j = threadIdx.x;
  size_t idx = (size_t)row*ND + j;
  float x = X[idx] + R[idx];
  float mu = bsum256(x) * (1.0f/ND);
  float d = x - mu;
  float var = bsum256(d*d) * (1.0f/ND);
  float y = d * rsqrtf(var + 1e-6f) * g[j] + bta[j];
  Yf[idx] = y;
  Yb[idx] = f2b(y);
}

// ---------------- relay attention phase 1: split-K partials, fused kr|vr bf16 [B][4097][512] ----------------
__global__ __launch_bounds__(256) void rel_part(const float* __restrict__ QR,
    const ushort_t* __restrict__ KRV,
    float* __restrict__ pO, float* __restrict__ pM, float* __restrict__ pL)
{
  const int bh = blockIdx.x;
  const int b = bh >> 3, h = bh & 7;
  const int c = blockIdx.y;
  const int k0 = c*CH;
  const int kn = min(NK, k0+CH) - k0;
  const int tid = threadIdx.x;
  __shared__ float sc[CH];
  __shared__ float qs[NDK];
  __shared__ float red[8][NDK];
  if (tid < NDK) qs[tid] = QR[(size_t)b*ND + h*NDK + tid];
  __syncthreads();
  const float scale = 0.17677669529663687f;
  for (int kk=tid; kk<kn; kk+=256){
    const ushort_t* kp = KRV + ((size_t)b*NK + k0 + kk)*512 + h*NDK;
    float sdot = 0.f;
    #pragma unroll
    for (int w=0; w<4; w++){
      bf16x8 kv = *(const bf16x8*)(kp + w*8);
      #pragma unroll
      for (int i=0;i<8;i++) sdot = fmaf(qs[w*8+i], b2f((ushort_t)kv[i]), sdot);
    }
    sc[kk] = sdot * scale;
  }
  __syncthreads();
  float lm = -1e30f;
  for (int kk=tid; kk<kn; kk+=256) lm = fmaxf(lm, sc[kk]);
  float m = bmax256(lm);
  float ls = 0.f;
  for (int kk=tid; kk<kn; kk+=256){ float p = expf(sc[kk]-m); sc[kk] = p; ls += p; }
  float lsum = bsum256(ls);
  int grp = tid>>5, d = tid&31;
  float acc = 0.f;
  for (int kk=grp; kk<kn; kk+=8)
    acc = fmaf(sc[kk], b2f(KRV[((size_t)b*NK + k0 + kk)*512 + 256 + h*NDK + d]), acc);
  red[grp][d] = acc;
  __syncthreads();
  if (grp == 0){
    float tot = 0.f;
    #pragma unroll
    for (int i=0;i<8;i++) tot += red[i][d];
    pO[((size_t)bh*NCH + c)*NDK + d] = tot;
    if (d == 0){ pM[bh*NCH + c] = m; pL[bh*NCH + c] = lsum; }
  }
}

// ---------------- relay attention phase 2: online-softmax merge ----------------
__global__ __launch_bounds__(256) void rel_merge(const float* __restrict__ pO,
    const float* __restrict__ pM, const float* __restrict__ pL, float* __restrict__ ORL)
{
  const int b = blockIdx.x;
  const int h = threadIdx.x >> 5, d = threadIdx.x & 31;
  const int bh = b*NH + h;
  float m = -1e30f;
  #pragma unroll
  for (int c=0;c<NCH;c++) m = fmaxf(m, pM[bh*NCH + c]);
  float o = 0.f, l = 0.f;
  #pragma unroll
  for (int c=0;c<NCH;c++){
    float w = expf(pM[bh*NCH + c] - m);
    o = fmaf(pO[((size_t)bh*NCH + c)*NDK + d], w, o);
    l = fmaf(pL[bh*NCH + c], w, l);
  }
  ORL[(size_t)b*ND + h*NDK + d] = o / l;
}

// ---------------- relay output: orl@wo + s -> LN -> f32 tail of out ----------------
__global__ __launch_bounds__(256) void rel_out(const float* __restrict__ ORL,
    const float* __restrict__ WO, const float* __restrict__ Sv,
    const float* __restrict__ g, const float* __restrict__ bta,
    float* __restrict__ out)
{
  int b = blockIdx.x, j = threadIdx.x;
  __shared__ float ol[ND];
  ol[j] = ORL[(size_t)b*ND + j];
  __syncthreads();
  float x = 0.f;
  for (int d=0; d<ND; d++) x = fmaf(ol[d], WO[(size_t)d*ND + j], x);
  x += Sv[(size_t)b*ND + j];
  float mu = bsum256(x) * (1.0f/ND);
  float dd = x - mu;
  float var = bsum256(dd*dd) * (1.0f/ND);
  out[(size_t)NBS*ND + (size_t)b*ND + j] = dd * rsqrtf(var + 1e-6f) * g[j] + bta[j];
}

extern "C" void kernel_launch(void* const* d_in, const int* in_sizes, int n_in,
                              void* d_out, int out_size, void* d_ws, size_t ws_size,
                              hipStream_t stream)
{
  const float* h      = (const float*)d_in[0];
  const float* e      = (const float*)d_in[1];
  const float* s      = (const float*)d_in[2];
  const float* sat_wq = (const float*)d_in[3];
  const float* sat_wk = (const float*)d_in[4];
  const float* sat_wv = (const float*)d_in[5];
  const float* sat_wo = (const float*)d_in[6];
  const float* sat_g  = (const float*)d_in[7];
  const float* sat_b  = (const float*)d_in[8];
  const float* rel_wq = (const float*)d_in[9];
  const float* rel_wk = (const float*)d_in[10];
  const float* rel_wv = (const float*)d_in[11];
  const float* rel_wo = (const float*)d_in[12];
  const float* rel_g  = (const float*)d_in[13];
  const float* rel_b  = (const float*)d_in[14];
  float* out = (float*)d_out;

  float* ws = (float*)d_ws;
  // float-offset layout (~222 MB; r4 proved >=236 MB available):
  ushort_t* hQKV = (ushort_t*)ws;                    // [0,1.5P) bf16 [M][768] q|kh|vh
  ushort_t* h16  = (ushort_t*)(ws + (3*PBUF)/2);     // [1.5P,2P) bf16 h
  ushort_t* eKV  = (ushort_t*)(ws + 2*PBUF);         // [2P,3P) bf16 [M][512] ke|ve
  float*    oprj = ws + 3*PBUF;                      // [3P,4P) f32
  ushort_t* krv  = (ushort_t*)(ws + 4*PBUF);         // [4P,5P) bf16 [B][4097][512] kr|vr
  ushort_t* hb   = (ushort_t*)(ws + 5*PBUF);         // [5P,5.5P) bf16 h_out
  ushort_t* satO = hb + HSZ;                         // [5.5P,6P) bf16 sat-attn out
  ushort_t* e16  = satO + HSZ;                       // [6P,6.5P) bf16 e
  ushort_t* Wt   = e16 + HSZ;                        // 6 transposed bf16 weights
  float* smalls  = (float*)(Wt + 6*65536);
  ushort_t* ksb = (ushort_t*)smalls;
  ushort_t* vsb = ksb + 2048;
  float* qr  = smalls + 4096;
  float* orl = smalls + 6144;
  float* pO  = smalls + 8192;
  float* pM  = pO + (size_t)NB*NH*NCH*NDK;
  float* pL  = pM + NB*NH*NCH;

  dim3 tgrid(4,4), gb(256);

  // transposed bf16 weights: q,k,v,o,rk,rv
  transp_w<<<tgrid, gb, 0, stream>>>(sat_wq, Wt);
  transp_w<<<tgrid, gb, 0, stream>>>(sat_wk, Wt + 1*65536);
  transp_w<<<tgrid, gb, 0, stream>>>(sat_wv, Wt + 2*65536);
  transp_w<<<tgrid, gb, 0, stream>>>(sat_wo, Wt + 3*65536);
  transp_w<<<tgrid, gb, 0, stream>>>(rel_wk, Wt + 4*65536);
  transp_w<<<tgrid, gb, 0, stream>>>(rel_wv, Wt + 5*65536);
  cvtbf16<<<4096, gb, 0, stream>>>(h, h16);
  cvtbf16<<<4096, gb, 0, stream>>>(e, e16);

  // fused projections (MFMA + global_load_lds + dbuf)
  gemm_lds<1><<<dim3(NBS/128, 6), gb, 0, stream>>>(h16, Wt,           hQKV, 768, 0); // q|kh|vh
  gemm_lds<1><<<dim3(NBS/128, 4), gb, 0, stream>>>(e16, Wt + 1*65536, eKV,  512, 0); // ke|ve
  rowgemm_b16<<<NB, gb, 0, stream>>>(s, sat_wk, ksb, 256, 0, 0);
  rowgemm_b16<<<NB, gb, 0, stream>>>(s, sat_wv, vsb, 256, 0, 0);

  // satellite attention + oproj + LN
  sat_attn4<<<NBS/8, gb, 0, stream>>>(hQKV, eKV, ksb, vsb, satO);
  gemm_lds<0><<<dim3(NBS/128, 2), gb, 0, stream>>>(satO, Wt + 3*65536, oprj, 256, 0);
  add_ln<<<NBS, gb, 0, stream>>>(oprj, h, sat_g, sat_b, out, hb);  // f32 -> out, bf16 -> hb

  // relay: q from s; fused kr|vr over [s; h_out]
  rowgemm<<<NB, gb, 0, stream>>>(s, rel_wq, qr);
  rowgemm_b16<<<NB, gb, 0, stream>>>(s, rel_wk, krv, 512, 0,   2); // row 0 kr
  rowgemm_b16<<<NB, gb, 0, stream>>>(s, rel_wv, krv, 512, 256, 2); // row 0 vr
  gemm_lds<1><<<dim3(NBS/128, 4), gb, 0, stream>>>(hb, Wt + 4*65536, krv, 512, 1);
  rel_part<<<dim3(NB*NH, NCH), gb, 0, stream>>>(qr, krv, pO, pM, pL);
  rel_merge<<<NB, gb, 0, stream>>>(pO, pM, pL, orl);
  rel_out<<<NB, gb, 0, stream>>>(orl, rel_wo, s, rel_g, rel_b, out);
}

// Round 10
// 207.736 us; speedup vs baseline: 11.6320x; 1.3273x over previous
//
#include <hip/hip_runtime.h>
#include <hip/hip_bf16.h>

typedef unsigned short ushort_t;
typedef unsigned int uint_t;
typedef __attribute__((ext_vector_type(8))) short bf16x8;
typedef __attribute__((ext_vector_type(4))) float f32x4;

#define NB 8
#define NS 4096
#define ND 256
#define NH 8
#define NDK 32
#define NBS (NB*NS)                       // 32768 rows
#define NK  (NS+1)                        // 4097 relay keys
#define CH  513                           // relay split-K chunk
#define NCH 8
static const size_t PBUF = (size_t)NB*(NS+1)*ND;   // 8,390,656 floats per big f32 buffer
static const size_t HSZ  = (size_t)NBS*ND;         // 8,388,608 elems (bf16 buffers)

__device__ __forceinline__ ushort_t f2b(float x){
  union { __hip_bfloat16 b; ushort_t u; } cv; cv.b = __float2bfloat16(x); return cv.u;
}
__device__ __forceinline__ float b2f(ushort_t u){
  union { uint_t u; float f; } cv; cv.u = ((uint_t)u) << 16; return cv.f;
}

// async global->LDS, 16B per lane, wave-uniform LDS base + lane*16
__device__ __forceinline__ void gload16(const ushort_t* g, ushort_t* l){
  __builtin_amdgcn_global_load_lds(
      (const __attribute__((address_space(1))) void*)g,
      (__attribute__((address_space(3))) void*)l, 16, 0, 0);
}

// ---------------- block reduce helpers (blockDim.x == 256) ----------------
__device__ __forceinline__ float bsum256(float v){
  __shared__ float tmp[4];
  #pragma unroll
  for (int o=32;o>0;o>>=1) v += __shfl_down(v,o);
  if ((threadIdx.x & 63)==0) tmp[threadIdx.x>>6] = v;
  __syncthreads();
  float r = tmp[0]+tmp[1]+tmp[2]+tmp[3];
  __syncthreads();
  return r;
}
__device__ __forceinline__ float bmax256(float v){
  __shared__ float tmp[4];
  #pragma unroll
  for (int o=32;o>0;o>>=1) v = fmaxf(v, __shfl_down(v,o));
  if ((threadIdx.x & 63)==0) tmp[threadIdx.x>>6] = v;
  __syncthreads();
  float r = fmaxf(fmaxf(tmp[0],tmp[1]),fmaxf(tmp[2],tmp[3]));
  __syncthreads();
  return r;
}

// ---------------- all 6 weight transposes in one launch: grid (4,4,6) ----------------
__global__ __launch_bounds__(256) void transp_all(
    const float* __restrict__ w0, const float* __restrict__ w1, const float* __restrict__ w2,
    const float* __restrict__ w3, const float* __restrict__ w4, const float* __restrict__ w5,
    ushort_t* __restrict__ WtAll)
{
  const int z = blockIdx.z;
  const float* W = (z==0)?w0:(z==1)?w1:(z==2)?w2:(z==3)?w3:(z==4)?w4:w5;
  ushort_t* Wt = WtAll + (size_t)z*65536;
  __shared__ float t[64][68];
  const int k0 = blockIdx.x*64, n0 = blockIdx.y*64;
  const int tr = threadIdx.x>>4, tc4 = (threadIdx.x&15)*4;
  #pragma unroll
  for (int i=0;i<4;i++){
    int r = tr + i*16;
    float4 v = *(const float4*)&W[(size_t)(k0+r)*ND + n0 + tc4];
    t[r][tc4]=v.x; t[r][tc4+1]=v.y; t[r][tc4+2]=v.z; t[r][tc4+3]=v.w;
  }
  __syncthreads();
  #pragma unroll
  for (int i=0;i<4;i++){
    int n = tr + i*16;
    uint_t q0 = f2b(t[tc4+0][n]) | ((uint_t)f2b(t[tc4+1][n])<<16);
    uint_t q1 = f2b(t[tc4+2][n]) | ((uint_t)f2b(t[tc4+3][n])<<16);
    *(uint2*)&Wt[(size_t)(n0+n)*ND + k0 + tc4] = make_uint2(q0,q1);
  }
}

// ---------------- f32 -> bf16 convert (8 elems/thread) ----------------
__global__ __launch_bounds__(256) void cvtbf16(const float* __restrict__ X, ushort_t* __restrict__ Y)
{
  size_t i = ((size_t)blockIdx.x*256 + threadIdx.x)*8;
  float4 a = *(const float4*)(X+i), b = *(const float4*)(X+i+4);
  uint4 o;
  o.x = f2b(a.x) | ((uint_t)f2b(a.y)<<16);
  o.y = f2b(a.z) | ((uint_t)f2b(a.w)<<16);
  o.z = f2b(b.x) | ((uint_t)f2b(b.y)<<16);
  o.w = f2b(b.z) | ((uint_t)f2b(b.w)<<16);
  *(uint4*)(Y+i) = o;
}

// ---------------- bf16 MFMA GEMM, gload_lds + XOR-swizzled LDS (conflict-free), BK=64 ----------
// A[M,256] bf16 @ Wt[ldn][256] bf16(T) -> Y[M,ldn]. OBF16: bf16 out else f32.
// remap 1: output row r -> (r>>12)*4097 + 1 + (r&4095)
// Swizzle: logical byte (row*128 + c) stored at physical (row*128 + (c ^ ((row&7)<<4))).
// Write side via pre-swizzled global slot ls=(l&7)^(l>>3); read side via XOR on frag address.
template<int OBF16>
__global__ __launch_bounds__(256) void gemm_xor(const ushort_t* __restrict__ A,
    const ushort_t* __restrict__ Wt, void* __restrict__ Yv, int ldn, int remap)
{
  __shared__ __align__(16) ushort_t As[2][128][64];   // 16KB per buffer
  __shared__ __align__(16) ushort_t Bs[2][128][64];
  const int tid  = threadIdx.x;
  const int row0 = blockIdx.x*128;
  const int col0 = blockIdx.y*128;
  const int lane = tid & 63;
  const int wave = tid >> 6;
  const int wr = (wave>>1)*64, wc = (wave&1)*64;
  const int l15 = lane & 15, lg = lane >> 4;
  const int lr8 = lane >> 3;                 // row within 8-row staging group
  const int ls  = (lane & 7) ^ lr8;          // pre-swizzled 16B slot

  const ushort_t* Asrc = A  + (size_t)(row0 + wave*32 + lr8)*ND + ls*8;
  const ushort_t* Bsrc = Wt + (size_t)(col0 + wave*32 + lr8)*ND + ls*8;

  f32x4 acc[4][4] = {};

  #define STAGE(t, bb) do{ \
    _Pragma("unroll") \
    for (int i=0;i<4;i++){ \
      gload16(Asrc + (size_t)i*8*ND + (t)*64, &As[bb][wave*32+i*8][0]); \
      gload16(Bsrc + (size_t)i*8*ND + (t)*64, &Bs[bb][wave*32+i*8][0]); \
    } \
  }while(0)

  #define COMPUTE(bb) do{ \
    _Pragma("unroll") \
    for (int ks=0; ks<2; ks++){ \
      bf16x8 af[4], bfr[4]; \
      _Pragma("unroll") \
      for (int mi=0;mi<4;mi++){ \
        int ra = wr + mi*16 + l15; \
        int cb = (ks<<6) + (lg<<4); \
        af[mi] = *(const bf16x8*)((const char*)&As[bb][0][0] + ra*128 + (cb ^ ((ra&7)<<4))); \
      } \
      _Pragma("unroll") \
      for (int ni=0;ni<4;ni++){ \
        int rb = wc + ni*16 + l15; \
        int cb = (ks<<6) + (lg<<4); \
        bfr[ni] = *(const bf16x8*)((const char*)&Bs[bb][0][0] + rb*128 + (cb ^ ((rb&7)<<4))); \
      } \
      _Pragma("unroll") \
      for (int mi=0;mi<4;mi++) \
        _Pragma("unroll") \
        for (int ni=0;ni<4;ni++) \
          acc[mi][ni] = __builtin_amdgcn_mfma_f32_16x16x32_bf16(af[mi], bfr[ni], acc[mi][ni], 0,0,0); \
    } \
  }while(0)

  STAGE(0, 0);
  __syncthreads();
  STAGE(1, 1); COMPUTE(0); __syncthreads();
  STAGE(2, 0); COMPUTE(1); __syncthreads();
  STAGE(3, 1); COMPUTE(0); __syncthreads();
  COMPUTE(1);
  #undef STAGE
  #undef COMPUTE

  #pragma unroll
  for (int mi=0;mi<4;mi++){
    #pragma unroll
    for (int r=0;r<4;r++){
      int row = row0 + wr + mi*16 + lg*4 + r;
      size_t orow = remap ? (size_t)(row>>12)*(NS+1) + 1 + (row&4095) : (size_t)row;
      #pragma unroll
      for (int ni=0;ni<4;ni++){
        size_t idx = orow*(size_t)ldn + col0 + wc + ni*16 + l15;
        if (OBF16) ((ushort_t*)Yv)[idx] = f2b(acc[mi][ni][r]);
        else       ((float*)Yv)[idx]    = acc[mi][ni][r];
      }
    }
  }
}

// ---------------- all 5 s-projections in one launch: grid (NB, 5) ----------------
// y=0: ks(bf16) ; y=1: vs(bf16) ; y=2: qr(f32) ; y=3: krv row0 K ; y=4: krv row0 V
__global__ __launch_bounds__(256) void sproj_all(const float* __restrict__ s,
    const float* __restrict__ swk, const float* __restrict__ swv,
    const float* __restrict__ rwq, const float* __restrict__ rwk, const float* __restrict__ rwv,
    ushort_t* __restrict__ ksb, ushort_t* __restrict__ vsb,
    float* __restrict__ qr, ushort_t* __restrict__ krv)
{
  const int b = blockIdx.x, which = blockIdx.y, j = threadIdx.x;
  const float* W = (which==0)?swk:(which==1)?swv:(which==2)?rwq:(which==3)?rwk:rwv;
  __shared__ float a[ND];
  a[j] = s[(size_t)b*ND + j];
  __syncthreads();
  float acc = 0.f;
  #pragma unroll 8
  for (int d=0; d<ND; d++)
    acc = fmaf(a[d], W[(size_t)d*ND + j], acc);
  switch (which){
    case 0: ksb[(size_t)b*ND + j] = f2b(acc); break;
    case 1: vsb[(size_t)b*ND + j] = f2b(acc); break;
    case 2: qr[(size_t)b*ND + j] = acc; break;
    case 3: krv[(size_t)b*NK*512 + j] = f2b(acc); break;
    default: krv[(size_t)b*NK*512 + 256 + j] = f2b(acc); break;
  }
}

// ---------------- satellite attention v4: 4-lane groups, bf16x8 vector loads ----------------
__device__ __forceinline__ void load8(float* d, const ushort_t* p){
  bf16x8 v = *(const bf16x8*)p;
  #pragma unroll
  for (int i=0;i<8;i++) d[i] = b2f((ushort_t)v[i]);
}
__device__ __forceinline__ void zero8(float* d){
  #pragma unroll
  for (int i=0;i<8;i++) d[i] = 0.f;
}
__global__ __launch_bounds__(256) void sat_attn4(const ushort_t* __restrict__ HQ,
    const ushort_t* __restrict__ EKV,
    const ushort_t* __restrict__ KS, const ushort_t* __restrict__ VS,
    ushort_t* __restrict__ O)
{
  const int tid = threadIdx.x;
  const int l  = tid & 3;
  const int g  = tid >> 2;
  const int hh = g & 7;
  const int pi = g >> 3;
  const int pos = blockIdx.x*8 + pi;
  const int b = pos >> 12, t = pos & 4095;
  const int co = hh*NDK + l*8;
  const float scale = 0.17677669529663687f;

  const size_t rq = (size_t)pos*768;
  const size_t re = (size_t)pos*512;
  float q[8], k0[8], k1[8], k2[8], k3[8], k4[8];
  load8(q,  HQ + rq + co);
  load8(k1, HQ + rq + 256 + co);
  load8(k3, EKV + re + co);
  load8(k4, KS + (size_t)b*ND + co);
  if (t > 0)    load8(k0, HQ + rq - 768 + 256 + co);
  else          zero8(k0);
  if (t < NS-1) load8(k2, HQ + rq + 768 + 256 + co);
  else          zero8(k2);

  float s0=0.f,s1=0.f,s2=0.f,s3=0.f,s4=0.f;
  #pragma unroll
  for (int i=0;i<8;i++){
    s0 = fmaf(q[i],k0[i],s0); s1 = fmaf(q[i],k1[i],s1); s2 = fmaf(q[i],k2[i],s2);
    s3 = fmaf(q[i],k3[i],s3); s4 = fmaf(q[i],k4[i],s4);
  }
  #pragma unroll
  for (int mm=1; mm<4; mm<<=1){
    s0 += __shfl_xor(s0,mm); s1 += __shfl_xor(s1,mm); s2 += __shfl_xor(s2,mm);
    s3 += __shfl_xor(s3,mm); s4 += __shfl_xor(s4,mm);
  }
  s0*=scale; s1*=scale; s2*=scale; s3*=scale; s4*=scale;
  float m = fmaxf(fmaxf(fmaxf(s0,s1),fmaxf(s2,s3)),s4);
  float p0=expf(s0-m), p1=expf(s1-m), p2=expf(s2-m), p3=expf(s3-m), p4=expf(s4-m);
  float inv = 1.0f/(p0+p1+p2+p3+p4);

  float v0[8], v1[8], v2[8], v3[8], v4[8];
  load8(v1, HQ + rq + 512 + co);
  load8(v3, EKV + re + 256 + co);
  load8(v4, VS + (size_t)b*ND + co);
  if (t > 0)    load8(v0, HQ + rq - 768 + 512 + co);
  else          zero8(v0);
  if (t < NS-1) load8(v2, HQ + rq + 768 + 512 + co);
  else          zero8(v2);

  float o[8];
  #pragma unroll
  for (int i=0;i<8;i++)
    o[i] = (p0*v0[i] + p1*v1[i] + p2*v2[i] + p3*v3[i] + p4*v4[i]) * inv;
  uint4 pk;
  pk.x = f2b(o[0])|((uint_t)f2b(o[1])<<16);
  pk.y = f2b(o[2])|((uint_t)f2b(o[3])<<16);
  pk.z = f2b(o[4])|((uint_t)f2b(o[5])<<16);
  pk.w = f2b(o[6])|((uint_t)f2b(o[7])<<16);
  *(uint4*)&O[(size_t)pos*ND + co] = pk;
}

// ---------------- residual add + LayerNorm -> f32 out + bf16 copy ----------------
__global__ __launch_bounds__(256) void add_ln(const float* __restrict__ X,
    const float* __restrict__ R, const float* __restrict__ g, const float* __restrict__ bta,
    float* __restrict__ Yf, ushort_t* __restrict__ Yb)
{
  int row = blockIdx.x, j = threadIdx.x;
  size_t idx = (size_t)row*ND + j;
  float x = X[idx] + R[idx];
  float mu = bsum256(x) * (1.0f/ND);
  float d = x - mu;
  float var = bsum256(d*d) * (1.0f/ND);
  float y = d * rsqrtf(var + 1e-6f) * g[j] + bta[j];
  Yf[idx] = y;
  Yb[idx] = f2b(y);
}

// ---------------- relay attention phase 1: split-K partials, fused kr|vr bf16 [B][4097][512] ----------------
__global__ __launch_bounds__(256) void rel_part(const float* __restrict__ QR,
    const ushort_t* __restrict__ KRV,
    float* __restrict__ pO, float* __restrict__ pM, float* __restrict__ pL)
{
  const int bh = blockIdx.x;
  const int b = bh >> 3, h = bh & 7;
  const int c = blockIdx.y;
  const int k0 = c*CH;
  const int kn = min(NK, k0+CH) - k0;
  const int tid = threadIdx.x;
  __shared__ float sc[CH];
  __shared__ float qs[NDK];
  __shared__ float red[8][NDK];
  if (tid < NDK) qs[tid] = QR[(size_t)b*ND + h*NDK + tid];
  __syncthreads();
  const float scale = 0.17677669529663687f;
  for (int kk=tid; kk<kn; kk+=256){
    const ushort_t* kp = KRV + ((size_t)b*NK + k0 + kk)*512 + h*NDK;
    float sdot = 0.f;
    #pragma unroll
    for (int w=0; w<4; w++){
      bf16x8 kv = *(const bf16x8*)(kp + w*8);
      #pragma unroll
      for (int i=0;i<8;i++) sdot = fmaf(qs[w*8+i], b2f((ushort_t)kv[i]), sdot);
    }
    sc[kk] = sdot * scale;
  }
  __syncthreads();
  float lm = -1e30f;
  for (int kk=tid; kk<kn; kk+=256) lm = fmaxf(lm, sc[kk]);
  float m = bmax256(lm);
  float ls = 0.f;
  for (int kk=tid; kk<kn; kk+=256){ float p = expf(sc[kk]-m); sc[kk] = p; ls += p; }
  float lsum = bsum256(ls);
  int grp = tid>>5, d = tid&31;
  float acc = 0.f;
  for (int kk=grp; kk<kn; kk+=8)
    acc = fmaf(sc[kk], b2f(KRV[((size_t)b*NK + k0 + kk)*512 + 256 + h*NDK + d]), acc);
  red[grp][d] = acc;
  __syncthreads();
  if (grp == 0){
    float tot = 0.f;
    #pragma unroll
    for (int i=0;i<8;i++) tot += red[i][d];
    pO[((size_t)bh*NCH + c)*NDK + d] = tot;
    if (d == 0){ pM[bh*NCH + c] = m; pL[bh*NCH + c] = lsum; }
  }
}

// ---------------- relay attention phase 2: online-softmax merge ----------------
__global__ __launch_bounds__(256) void rel_merge(const float* __restrict__ pO,
    const float* __restrict__ pM, const float* __restrict__ pL, float* __restrict__ ORL)
{
  const int b = blockIdx.x;
  const int h = threadIdx.x >> 5, d = threadIdx.x & 31;
  const int bh = b*NH + h;
  float m = -1e30f;
  #pragma unroll
  for (int c=0;c<NCH;c++) m = fmaxf(m, pM[bh*NCH + c]);
  float o = 0.f, l = 0.f;
  #pragma unroll
  for (int c=0;c<NCH;c++){
    float w = expf(pM[bh*NCH + c] - m);
    o = fmaf(pO[((size_t)bh*NCH + c)*NDK + d], w, o);
    l = fmaf(pL[bh*NCH + c], w, l);
  }
  ORL[(size_t)b*ND + h*NDK + d] = o / l;
}

// ---------------- relay output: orl@wo + s -> LN -> f32 tail of out ----------------
__global__ __launch_bounds__(256) void rel_out(const float* __restrict__ ORL,
    const float* __restrict__ WO, const float* __restrict__ Sv,
    const float* __restrict__ g, const float* __restrict__ bta,
    float* __restrict__ out)
{
  int b = blockIdx.x, j = threadIdx.x;
  __shared__ float ol[ND];
  ol[j] = ORL[(size_t)b*ND + j];
  __syncthreads();
  float x = 0.f;
  for (int d=0; d<ND; d++) x = fmaf(ol[d], WO[(size_t)d*ND + j], x);
  x += Sv[(size_t)b*ND + j];
  float mu = bsum256(x) * (1.0f/ND);
  float dd = x - mu;
  float var = bsum256(dd*dd) * (1.0f/ND);
  out[(size_t)NBS*ND + (size_t)b*ND + j] = dd * rsqrtf(var + 1e-6f) * g[j] + bta[j];
}

extern "C" void kernel_launch(void* const* d_in, const int* in_sizes, int n_in,
                              void* d_out, int out_size, void* d_ws, size_t ws_size,
                              hipStream_t stream)
{
  const float* h      = (const float*)d_in[0];
  const float* e      = (const float*)d_in[1];
  const float* s      = (const float*)d_in[2];
  const float* sat_wq = (const float*)d_in[3];
  const float* sat_wk = (const float*)d_in[4];
  const float* sat_wv = (const float*)d_in[5];
  const float* sat_wo = (const float*)d_in[6];
  const float* sat_g  = (const float*)d_in[7];
  const float* sat_b  = (const float*)d_in[8];
  const float* rel_wq = (const float*)d_in[9];
  const float* rel_wk = (const float*)d_in[10];
  const float* rel_wv = (const float*)d_in[11];
  const float* rel_wo = (const float*)d_in[12];
  const float* rel_g  = (const float*)d_in[13];
  const float* rel_b  = (const float*)d_in[14];
  float* out = (float*)d_out;

  float* ws = (float*)d_ws;
  ushort_t* hQKV = (ushort_t*)ws;                    // [0,1.5P) bf16 [M][768] q|kh|vh
  ushort_t* h16  = (ushort_t*)(ws + (3*PBUF)/2);     // [1.5P,2P) bf16 h
  ushort_t* eKV  = (ushort_t*)(ws + 2*PBUF);         // [2P,3P) bf16 [M][512] ke|ve
  float*    oprj = ws + 3*PBUF;                      // [3P,4P) f32
  ushort_t* krv  = (ushort_t*)(ws + 4*PBUF);         // [4P,5P) bf16 [B][4097][512] kr|vr
  ushort_t* hb   = (ushort_t*)(ws + 5*PBUF);         // [5P,5.5P) bf16 h_out
  ushort_t* satO = hb + HSZ;                         // [5.5P,6P) bf16 sat-attn out
  ushort_t* e16  = satO + HSZ;                       // [6P,6.5P) bf16 e
  ushort_t* Wt   = e16 + HSZ;                        // 6 transposed bf16 weights
  float* smalls  = (float*)(Wt + 6*65536);
  ushort_t* ksb = (ushort_t*)smalls;
  ushort_t* vsb = ksb + 2048;
  float* qr  = smalls + 4096;
  float* orl = smalls + 6144;
  float* pO  = smalls + 8192;
  float* pM  = pO + (size_t)NB*NH*NCH*NDK;
  float* pL  = pM + NB*NH*NCH;

  dim3 gb(256);

  // weights (q,k,v,o,rk,rv) + bf16 activations
  transp_all<<<dim3(4,4,6), gb, 0, stream>>>(sat_wq, sat_wk, sat_wv, sat_wo, rel_wk, rel_wv, Wt);
  cvtbf16<<<4096, gb, 0, stream>>>(h, h16);
  cvtbf16<<<4096, gb, 0, stream>>>(e, e16);

  // fused projections (MFMA, XOR-swizzled LDS)
  gemm_xor<1><<<dim3(NBS/128, 6), gb, 0, stream>>>(h16, Wt,           hQKV, 768, 0); // q|kh|vh
  gemm_xor<1><<<dim3(NBS/128, 4), gb, 0, stream>>>(e16, Wt + 1*65536, eKV,  512, 0); // ke|ve
  sproj_all<<<dim3(NB,5), gb, 0, stream>>>(s, sat_wk, sat_wv, rel_wq, rel_wk, rel_wv,
                                           ksb, vsb, qr, krv);

  // satellite attention + oproj + LN
  sat_attn4<<<NBS/8, gb, 0, stream>>>(hQKV, eKV, ksb, vsb, satO);
  gemm_xor<0><<<dim3(NBS/128, 2), gb, 0, stream>>>(satO, Wt + 3*65536, oprj, 256, 0);
  add_ln<<<NBS, gb, 0, stream>>>(oprj, h, sat_g, sat_b, out, hb);  // f32 -> out, bf16 -> hb

  // relay: fused kr|vr over [s; h_out]
  gemm_xor<1><<<dim3(NBS/128, 4), gb, 0, stream>>>(hb, Wt + 4*65536, krv, 512, 1);
  rel_part<<<dim3(NB*NH, NCH), gb, 0, stream>>>(qr, krv, pO, pM, pL);
  rel_merge<<<NB, gb, 0, stream>>>(pO, pM, pL, orl);
  rel_out<<<NB, gb, 0, stream>>>(orl, rel_wo, s, rel_g, rel_b, out);
}

// Round 11
// 175.224 us; speedup vs baseline: 13.7903x; 1.1855x over previous
//
#include <hip/hip_runtime.h>
#include <hip/hip_bf16.h>

typedef unsigned short ushort_t;
typedef unsigned int uint_t;
typedef __attribute__((ext_vector_type(8))) short bf16x8;
typedef __attribute__((ext_vector_type(4))) float f32x4;

#define NB 8
#define NS 4096
#define ND 256
#define NH 8
#define NDK 32
#define NBS (NB*NS)                       // 32768 rows
#define NK  (NS+1)                        // 4097 relay keys
#define CH  513                           // relay split-K chunk
#define NCH 8
static const size_t PBUF = (size_t)NB*(NS+1)*ND;   // 8,390,656 floats
static const size_t HSZ  = (size_t)NBS*ND;         // 8,388,608 elems

__device__ __forceinline__ ushort_t f2b(float x){
  union { __hip_bfloat16 b; ushort_t u; } cv; cv.b = __float2bfloat16(x); return cv.u;
}
__device__ __forceinline__ float b2f(ushort_t u){
  union { uint_t u; float f; } cv; cv.u = ((uint_t)u) << 16; return cv.f;
}
__device__ __forceinline__ void gload16(const ushort_t* g, ushort_t* l){
  __builtin_amdgcn_global_load_lds(
      (const __attribute__((address_space(1))) void*)g,
      (__attribute__((address_space(3))) void*)l, 16, 0, 0);
}

// ---------------- block reduce helpers (blockDim.x == 256) ----------------
__device__ __forceinline__ float bsum256(float v){
  __shared__ float tmp[4];
  #pragma unroll
  for (int o=32;o>0;o>>=1) v += __shfl_down(v,o);
  if ((threadIdx.x & 63)==0) tmp[threadIdx.x>>6] = v;
  __syncthreads();
  float r = tmp[0]+tmp[1]+tmp[2]+tmp[3];
  __syncthreads();
  return r;
}

// ---------------- prep: cvt h, cvt e, 6 weight transposes, 5 s-projections ----------------
// grid.x = 8328: [0,4096) cvt h; [4096,8192) cvt e; [8192,8288) transp; [8288,8328) sproj
__global__ __launch_bounds__(256) void prep(
    const float* __restrict__ h, const float* __restrict__ e,
    ushort_t* __restrict__ h16, ushort_t* __restrict__ e16,
    const float* __restrict__ w0, const float* __restrict__ w1, const float* __restrict__ w2,
    const float* __restrict__ w3, const float* __restrict__ w4, const float* __restrict__ w5,
    ushort_t* __restrict__ WtAll,
    const float* __restrict__ s,
    const float* __restrict__ rwq,
    ushort_t* __restrict__ ksb, ushort_t* __restrict__ vsb,
    float* __restrict__ qr, ushort_t* __restrict__ krv)
{
  __shared__ float sh[64*68];
  const int blk = blockIdx.x;
  const int tid = threadIdx.x;
  if (blk < 8192){
    const float* X = (blk < 4096) ? h : e;
    ushort_t*    Y = (blk < 4096) ? h16 : e16;
    size_t i = ((size_t)(blk & 4095)*256 + tid)*8;
    float4 a = *(const float4*)(X+i), b = *(const float4*)(X+i+4);
    uint4 o;
    o.x = f2b(a.x) | ((uint_t)f2b(a.y)<<16);
    o.y = f2b(a.z) | ((uint_t)f2b(a.w)<<16);
    o.z = f2b(b.x) | ((uint_t)f2b(b.y)<<16);
    o.w = f2b(b.z) | ((uint_t)f2b(b.w)<<16);
    *(uint4*)(Y+i) = o;
  } else if (blk < 8288){
    const int idx = blk - 8192;
    const int z = idx >> 4, xy = idx & 15;
    const float* W = (z==0)?w0:(z==1)?w1:(z==2)?w2:(z==3)?w3:(z==4)?w4:w5;
    ushort_t* Wt = WtAll + (size_t)z*65536;
    float (*t)[68] = (float(*)[68])sh;
    const int k0 = (xy>>2)*64, n0 = (xy&3)*64;
    const int tr = tid>>4, tc4 = (tid&15)*4;
    #pragma unroll
    for (int i=0;i<4;i++){
      int r = tr + i*16;
      float4 v = *(const float4*)&W[(size_t)(k0+r)*ND + n0 + tc4];
      t[r][tc4]=v.x; t[r][tc4+1]=v.y; t[r][tc4+2]=v.z; t[r][tc4+3]=v.w;
    }
    __syncthreads();
    #pragma unroll
    for (int i=0;i<4;i++){
      int n = tr + i*16;
      uint_t q0 = f2b(t[tc4+0][n]) | ((uint_t)f2b(t[tc4+1][n])<<16);
      uint_t q1 = f2b(t[tc4+2][n]) | ((uint_t)f2b(t[tc4+3][n])<<16);
      *(uint2*)&Wt[(size_t)(n0+n)*ND + k0 + tc4] = make_uint2(q0,q1);
    }
  } else {
    const int rem = blk - 8288;
    const int b = rem & 7, which = rem >> 3;      // 0:ks 1:vs 2:qr 3:krv-K0 4:krv-V0
    const float* W = (which==0)?w1:(which==1)?w2:(which==2)?rwq:(which==3)?w4:w5;
    float* a = sh;
    a[tid] = s[(size_t)b*ND + tid];
    __syncthreads();
    float acc = 0.f;
    #pragma unroll 8
    for (int d=0; d<ND; d++)
      acc = fmaf(a[d], W[(size_t)d*ND + tid], acc);
    switch (which){
      case 0: ksb[(size_t)b*ND + tid] = f2b(acc); break;
      case 1: vsb[(size_t)b*ND + tid] = f2b(acc); break;
      case 2: qr[(size_t)b*ND + tid] = acc; break;
      case 3: krv[(size_t)b*NK*512 + tid] = f2b(acc); break;
      default: krv[(size_t)b*NK*512 + 256 + tid] = f2b(acc); break;
    }
  }
}

// ---------------- fused projection GEMM: hQKV (y<6) + eKV (y>=6), bf16 out ----------------
__global__ __launch_bounds__(256) void gemm_qkve(const ushort_t* __restrict__ h16,
    const ushort_t* __restrict__ e16, const ushort_t* __restrict__ Wt,
    ushort_t* __restrict__ hQKV, ushort_t* __restrict__ eKV)
{
  __shared__ __align__(16) ushort_t As[2][128][64];
  __shared__ __align__(16) ushort_t Bs[2][128][64];
  const int y = blockIdx.y;
  const ushort_t* A; const ushort_t* Wb; ushort_t* Y; int ldn, col0;
  if (y < 6){ A=h16; Wb=Wt;        Y=hQKV; ldn=768; col0=y*128; }
  else      { A=e16; Wb=Wt+65536;  Y=eKV;  ldn=512; col0=(y-6)*128; }
  const int tid  = threadIdx.x;
  const int row0 = blockIdx.x*128;
  const int lane = tid & 63;
  const int wave = tid >> 6;
  const int wr = (wave>>1)*64, wc = (wave&1)*64;
  const int l15 = lane & 15, lg = lane >> 4;
  const int lr8 = lane >> 3;
  const int ls  = (lane & 7) ^ lr8;

  const ushort_t* Asrc = A  + (size_t)(row0 + wave*32 + lr8)*ND + ls*8;
  const ushort_t* Bsrc = Wb + (size_t)(col0 + wave*32 + lr8)*ND + ls*8;

  f32x4 acc[4][4] = {};

  #define STAGE(t, bb) do{ \
    _Pragma("unroll") \
    for (int i=0;i<4;i++){ \
      gload16(Asrc + (size_t)i*8*ND + (t)*64, &As[bb][wave*32+i*8][0]); \
      gload16(Bsrc + (size_t)i*8*ND + (t)*64, &Bs[bb][wave*32+i*8][0]); \
    } \
  }while(0)
  #define COMPUTE(bb) do{ \
    _Pragma("unroll") \
    for (int ks=0; ks<2; ks++){ \
      bf16x8 af[4], bfr[4]; \
      _Pragma("unroll") \
      for (int mi=0;mi<4;mi++){ \
        int ra = wr + mi*16 + l15; int cb = (ks<<6) + (lg<<4); \
        af[mi] = *(const bf16x8*)((const char*)&As[bb][0][0] + ra*128 + (cb ^ ((ra&7)<<4))); \
      } \
      _Pragma("unroll") \
      for (int ni=0;ni<4;ni++){ \
        int rb = wc + ni*16 + l15; int cb = (ks<<6) + (lg<<4); \
        bfr[ni] = *(const bf16x8*)((const char*)&Bs[bb][0][0] + rb*128 + (cb ^ ((rb&7)<<4))); \
      } \
      _Pragma("unroll") \
      for (int mi=0;mi<4;mi++) \
        _Pragma("unroll") \
        for (int ni=0;ni<4;ni++) \
          acc[mi][ni] = __builtin_amdgcn_mfma_f32_16x16x32_bf16(af[mi], bfr[ni], acc[mi][ni], 0,0,0); \
    } \
  }while(0)

  STAGE(0, 0);
  __syncthreads();
  STAGE(1, 1); COMPUTE(0); __syncthreads();
  STAGE(2, 0); COMPUTE(1); __syncthreads();
  STAGE(3, 1); COMPUTE(0); __syncthreads();
  COMPUTE(1);
  #undef STAGE
  #undef COMPUTE

  #pragma unroll
  for (int mi=0;mi<4;mi++)
    #pragma unroll
    for (int r=0;r<4;r++){
      size_t orow = (size_t)(row0 + wr + mi*16 + lg*4 + r);
      #pragma unroll
      for (int ni=0;ni<4;ni++)
        Y[orow*(size_t)ldn + col0 + wc + ni*16 + l15] = f2b(acc[mi][ni][r]);
    }
}

// ---------------- relay kr|vr GEMM (bf16 out, remapped rows) ----------------
__global__ __launch_bounds__(256) void gemm_krv(const ushort_t* __restrict__ A,
    const ushort_t* __restrict__ Wt, ushort_t* __restrict__ Y)
{
  __shared__ __align__(16) ushort_t As[2][128][64];
  __shared__ __align__(16) ushort_t Bs[2][128][64];
  const int tid  = threadIdx.x;
  const int row0 = blockIdx.x*128;
  const int col0 = blockIdx.y*128;
  const int lane = tid & 63;
  const int wave = tid >> 6;
  const int wr = (wave>>1)*64, wc = (wave&1)*64;
  const int l15 = lane & 15, lg = lane >> 4;
  const int lr8 = lane >> 3;
  const int ls  = (lane & 7) ^ lr8;

  const ushort_t* Asrc = A  + (size_t)(row0 + wave*32 + lr8)*ND + ls*8;
  const ushort_t* Bsrc = Wt + (size_t)(col0 + wave*32 + lr8)*ND + ls*8;

  f32x4 acc[4][4] = {};

  #define STAGE(t, bb) do{ \
    _Pragma("unroll") \
    for (int i=0;i<4;i++){ \
      gload16(Asrc + (size_t)i*8*ND + (t)*64, &As[bb][wave*32+i*8][0]); \
      gload16(Bsrc + (size_t)i*8*ND + (t)*64, &Bs[bb][wave*32+i*8][0]); \
    } \
  }while(0)
  #define COMPUTE(bb) do{ \
    _Pragma("unroll") \
    for (int ks=0; ks<2; ks++){ \
      bf16x8 af[4], bfr[4]; \
      _Pragma("unroll") \
      for (int mi=0;mi<4;mi++){ \
        int ra = wr + mi*16 + l15; int cb = (ks<<6) + (lg<<4); \
        af[mi] = *(const bf16x8*)((const char*)&As[bb][0][0] + ra*128 + (cb ^ ((ra&7)<<4))); \
      } \
      _Pragma("unroll") \
      for (int ni=0;ni<4;ni++){ \
        int rb = wc + ni*16 + l15; int cb = (ks<<6) + (lg<<4); \
        bfr[ni] = *(const bf16x8*)((const char*)&Bs[bb][0][0] + rb*128 + (cb ^ ((rb&7)<<4))); \
      } \
      _Pragma("unroll") \
      for (int mi=0;mi<4;mi++) \
        _Pragma("unroll") \
        for (int ni=0;ni<4;ni++) \
          acc[mi][ni] = __builtin_amdgcn_mfma_f32_16x16x32_bf16(af[mi], bfr[ni], acc[mi][ni], 0,0,0); \
    } \
  }while(0)

  STAGE(0, 0);
  __syncthreads();
  STAGE(1, 1); COMPUTE(0); __syncthreads();
  STAGE(2, 0); COMPUTE(1); __syncthreads();
  STAGE(3, 1); COMPUTE(0); __syncthreads();
  COMPUTE(1);
  #undef STAGE
  #undef COMPUTE

  #pragma unroll
  for (int mi=0;mi<4;mi++)
    #pragma unroll
    for (int r=0;r<4;r++){
      int row = row0 + wr + mi*16 + lg*4 + r;
      size_t orow = (size_t)(row>>12)*NK + 1 + (row&4095);
      #pragma unroll
      for (int ni=0;ni<4;ni++)
        Y[orow*512 + col0 + wc + ni*16 + l15] = f2b(acc[mi][ni][r]);
    }
}

// ---------------- oproj GEMM + residual + LayerNorm fused (BN=256) ----------------
// A=satO bf16 [M][256] @ Wto -> x; x += h; LN -> f32 out + bf16 hb
__global__ __launch_bounds__(256) void oproj_ln(const ushort_t* __restrict__ A,
    const ushort_t* __restrict__ Wt, const float* __restrict__ hres,
    const float* __restrict__ g, const float* __restrict__ bta,
    float* __restrict__ outf, ushort_t* __restrict__ outb)
{
  __shared__ __align__(16) ushort_t As[2][128][64];
  __shared__ __align__(16) ushort_t Bs[2][256][64];
  __shared__ float rs[128][2], rq[128][2];
  __shared__ float gl[ND], bl[ND];
  const int tid  = threadIdx.x;
  const int row0 = blockIdx.x*128;
  const int lane = tid & 63;
  const int wave = tid >> 6;
  const int wr = (wave>>1)*64, wc = (wave&1)*128;
  const int l15 = lane & 15, lg = lane >> 4;
  const int lr8 = lane >> 3;
  const int ls  = (lane & 7) ^ lr8;

  gl[tid] = g[tid]; bl[tid] = bta[tid];

  const ushort_t* Asrc = A  + (size_t)(row0 + wave*32 + lr8)*ND + ls*8;
  const ushort_t* Bsrc = Wt + (size_t)(wave*64 + lr8)*ND + ls*8;

  f32x4 acc[4][8] = {};

  #define STAGE2(t, bb) do{ \
    _Pragma("unroll") \
    for (int i=0;i<4;i++) \
      gload16(Asrc + (size_t)i*8*ND + (t)*64, &As[bb][wave*32+i*8][0]); \
    _Pragma("unroll") \
    for (int i=0;i<8;i++) \
      gload16(Bsrc + (size_t)i*8*ND + (t)*64, &Bs[bb][wave*64+i*8][0]); \
  }while(0)
  #define COMPUTE2(bb) do{ \
    _Pragma("unroll") \
    for (int ks=0; ks<2; ks++){ \
      bf16x8 af[4], bfr[8]; \
      _Pragma("unroll") \
      for (int mi=0;mi<4;mi++){ \
        int ra = wr + mi*16 + l15; int cb = (ks<<6) + (lg<<4); \
        af[mi] = *(const bf16x8*)((const char*)&As[bb][0][0] + ra*128 + (cb ^ ((ra&7)<<4))); \
      } \
      _Pragma("unroll") \
      for (int ni=0;ni<8;ni++){ \
        int rb = wc + ni*16 + l15; int cb = (ks<<6) + (lg<<4); \
        bfr[ni] = *(const bf16x8*)((const char*)&Bs[bb][0][0] + rb*128 + (cb ^ ((rb&7)<<4))); \
      } \
      _Pragma("unroll") \
      for (int mi=0;mi<4;mi++) \
        _Pragma("unroll") \
        for (int ni=0;ni<8;ni++) \
          acc[mi][ni] = __builtin_amdgcn_mfma_f32_16x16x32_bf16(af[mi], bfr[ni], acc[mi][ni], 0,0,0); \
    } \
  }while(0)

  STAGE2(0, 0);
  __syncthreads();
  STAGE2(1, 1); COMPUTE2(0); __syncthreads();
  STAGE2(2, 0); COMPUTE2(1); __syncthreads();
  STAGE2(3, 1); COMPUTE2(0); __syncthreads();
  COMPUTE2(1);
  #undef STAGE2
  #undef COMPUTE2

  // residual add (f32) into acc
  #pragma unroll
  for (int mi=0;mi<4;mi++)
    #pragma unroll
    for (int rr=0;rr<4;rr++){
      size_t rowb = (size_t)(row0 + wr + mi*16 + lg*4 + rr)*ND;
      #pragma unroll
      for (int ni=0;ni<8;ni++)
        acc[mi][ni][rr] += hres[rowb + wc + ni*16 + l15];
    }

  // per-row partials (sum, sumsq) over this wave's 128 cols; 16-lane shuffle reduce
  #pragma unroll
  for (int mi=0;mi<4;mi++)
    #pragma unroll
    for (int rr=0;rr<4;rr++){
      float sv = 0.f, qv = 0.f;
      #pragma unroll
      for (int ni=0;ni<8;ni++){ float x = acc[mi][ni][rr]; sv += x; qv += x*x; }
      #pragma unroll
      for (int o=1;o<16;o<<=1){ sv += __shfl_xor(sv,o); qv += __shfl_xor(qv,o); }
      if (l15 == 0){
        int rl = wr + mi*16 + lg*4 + rr;
        rs[rl][wave&1] = sv; rq[rl][wave&1] = qv;
      }
    }
  __syncthreads();

  // LN apply + dual write
  #pragma unroll
  for (int mi=0;mi<4;mi++)
    #pragma unroll
    for (int rr=0;rr<4;rr++){
      int rl = wr + mi*16 + lg*4 + rr;
      float sm = rs[rl][0] + rs[rl][1];
      float sq = rq[rl][0] + rq[rl][1];
      float mu = sm * (1.0f/ND);
      float var = sq * (1.0f/ND) - mu*mu;
      float rstd = rsqrtf(var + 1e-6f);
      size_t rowb = (size_t)(row0 + rl)*ND;
      #pragma unroll
      for (int ni=0;ni<8;ni++){
        int col = wc + ni*16 + l15;
        float yv = (acc[mi][ni][rr] - mu)*rstd*gl[col] + bl[col];
        outf[rowb + col] = yv;
        outb[rowb + col] = f2b(yv);
      }
    }
}

// ---------------- satellite attention v4: 4-lane groups, bf16x8 vector loads ----------------
__device__ __forceinline__ void load8(float* d, const ushort_t* p){
  bf16x8 v = *(const bf16x8*)p;
  #pragma unroll
  for (int i=0;i<8;i++) d[i] = b2f((ushort_t)v[i]);
}
__device__ __forceinline__ void zero8(float* d){
  #pragma unroll
  for (int i=0;i<8;i++) d[i] = 0.f;
}
__global__ __launch_bounds__(256) void sat_attn4(const ushort_t* __restrict__ HQ,
    const ushort_t* __restrict__ EKV,
    const ushort_t* __restrict__ KS, const ushort_t* __restrict__ VS,
    ushort_t* __restrict__ O)
{
  const int tid = threadIdx.x;
  const int l  = tid & 3;
  const int g  = tid >> 2;
  const int hh = g & 7;
  const int pi = g >> 3;
  const int pos = blockIdx.x*8 + pi;
  const int b = pos >> 12, t = pos & 4095;
  const int co = hh*NDK + l*8;
  const float scale = 0.17677669529663687f;

  const size_t rq = (size_t)pos*768;
  const size_t re = (size_t)pos*512;
  float q[8], k0[8], k1[8], k2[8], k3[8], k4[8];
  load8(q,  HQ + rq + co);
  load8(k1, HQ + rq + 256 + co);
  load8(k3, EKV + re + co);
  load8(k4, KS + (size_t)b*ND + co);
  if (t > 0)    load8(k0, HQ + rq - 768 + 256 + co);
  else          zero8(k0);
  if (t < NS-1) load8(k2, HQ + rq + 768 + 256 + co);
  else          zero8(k2);

  float s0=0.f,s1=0.f,s2=0.f,s3=0.f,s4=0.f;
  #pragma unroll
  for (int i=0;i<8;i++){
    s0 = fmaf(q[i],k0[i],s0); s1 = fmaf(q[i],k1[i],s1); s2 = fmaf(q[i],k2[i],s2);
    s3 = fmaf(q[i],k3[i],s3); s4 = fmaf(q[i],k4[i],s4);
  }
  #pragma unroll
  for (int mm=1; mm<4; mm<<=1){
    s0 += __shfl_xor(s0,mm); s1 += __shfl_xor(s1,mm); s2 += __shfl_xor(s2,mm);
    s3 += __shfl_xor(s3,mm); s4 += __shfl_xor(s4,mm);
  }
  s0*=scale; s1*=scale; s2*=scale; s3*=scale; s4*=scale;
  float m = fmaxf(fmaxf(fmaxf(s0,s1),fmaxf(s2,s3)),s4);
  float p0=expf(s0-m), p1=expf(s1-m), p2=expf(s2-m), p3=expf(s3-m), p4=expf(s4-m);
  float inv = 1.0f/(p0+p1+p2+p3+p4);

  float v0[8], v1[8], v2[8], v3[8], v4[8];
  load8(v1, HQ + rq + 512 + co);
  load8(v3, EKV + re + 256 + co);
  load8(v4, VS + (size_t)b*ND + co);
  if (t > 0)    load8(v0, HQ + rq - 768 + 512 + co);
  else          zero8(v0);
  if (t < NS-1) load8(v2, HQ + rq + 768 + 512 + co);
  else          zero8(v2);

  float o[8];
  #pragma unroll
  for (int i=0;i<8;i++)
    o[i] = (p0*v0[i] + p1*v1[i] + p2*v2[i] + p3*v3[i] + p4*v4[i]) * inv;
  uint4 pk;
  pk.x = f2b(o[0])|((uint_t)f2b(o[1])<<16);
  pk.y = f2b(o[2])|((uint_t)f2b(o[3])<<16);
  pk.z = f2b(o[4])|((uint_t)f2b(o[5])<<16);
  pk.w = f2b(o[6])|((uint_t)f2b(o[7])<<16);
  *(uint4*)&O[(size_t)pos*ND + co] = pk;
}

// ---------------- relay attention phase 1: split-K partials over fused krv ----------------
__global__ __launch_bounds__(256) void rel_part(const float* __restrict__ QR,
    const ushort_t* __restrict__ KRV,
    float* __restrict__ pO, float* __restrict__ pM, float* __restrict__ pL)
{
  const int bh = blockIdx.x;
  const int b = bh >> 3, h = bh & 7;
  const int c = blockIdx.y;
  const int k0 = c*CH;
  const int kn = min(NK, k0+CH) - k0;
  const int tid = threadIdx.x;
  __shared__ float sc[CH];
  __shared__ float qs[NDK];
  __shared__ float red[8][NDK];
  __shared__ float tmp[4];
  if (tid < NDK) qs[tid] = QR[(size_t)b*ND + h*NDK + tid];
  __syncthreads();
  const float scale = 0.17677669529663687f;
  for (int kk=tid; kk<kn; kk+=256){
    const ushort_t* kp = KRV + ((size_t)b*NK + k0 + kk)*512 + h*NDK;
    float sdot = 0.f;
    #pragma unroll
    for (int w=0; w<4; w++){
      bf16x8 kv = *(const bf16x8*)(kp + w*8);
      #pragma unroll
      for (int i=0;i<8;i++) sdot = fmaf(qs[w*8+i], b2f((ushort_t)kv[i]), sdot);
    }
    sc[kk] = sdot * scale;
  }
  __syncthreads();
  float lm = -1e30f;
  for (int kk=tid; kk<kn; kk+=256) lm = fmaxf(lm, sc[kk]);
  #pragma unroll
  for (int o=32;o>0;o>>=1) lm = fmaxf(lm, __shfl_down(lm,o));
  if ((tid & 63)==0) tmp[tid>>6] = lm;
  __syncthreads();
  float m = fmaxf(fmaxf(tmp[0],tmp[1]),fmaxf(tmp[2],tmp[3]));
  __syncthreads();
  float ls = 0.f;
  for (int kk=tid; kk<kn; kk+=256){ float p = expf(sc[kk]-m); sc[kk] = p; ls += p; }
  #pragma unroll
  for (int o=32;o>0;o>>=1) ls += __shfl_down(ls,o);
  if ((tid & 63)==0) tmp[tid>>6] = ls;
  __syncthreads();
  float lsum = tmp[0]+tmp[1]+tmp[2]+tmp[3];
  int grp = tid>>5, d = tid&31;
  float acc = 0.f;
  for (int kk=grp; kk<kn; kk+=8)
    acc = fmaf(sc[kk], b2f(KRV[((size_t)b*NK + k0 + kk)*512 + 256 + h*NDK + d]), acc);
  red[grp][d] = acc;
  __syncthreads();
  if (grp == 0){
    float tot = 0.f;
    #pragma unroll
    for (int i=0;i<8;i++) tot += red[i][d];
    pO[((size_t)bh*NCH + c)*NDK + d] = tot;
    if (d == 0){ pM[bh*NCH + c] = m; pL[bh*NCH + c] = lsum; }
  }
}

// ---------------- relay tail: merge partials + wo matvec + LN -> s_out ----------------
__global__ __launch_bounds__(256) void rel_tail(const float* __restrict__ pO,
    const float* __restrict__ pM, const float* __restrict__ pL,
    const float* __restrict__ WO, const float* __restrict__ Sv,
    const float* __restrict__ g, const float* __restrict__ bta,
    float* __restrict__ out)
{
  const int b = blockIdx.x, j = threadIdx.x;
  __shared__ float ol[ND];
  {
    const int h = j >> 5, d = j & 31;
    const int bh = b*NH + h;
    float m = -1e30f;
    #pragma unroll
    for (int c=0;c<NCH;c++) m = fmaxf(m, pM[bh*NCH + c]);
    float o = 0.f, l = 0.f;
    #pragma unroll
    for (int c=0;c<NCH;c++){
      float w = expf(pM[bh*NCH + c] - m);
      o = fmaf(pO[((size_t)bh*NCH + c)*NDK + d], w, o);
      l = fmaf(pL[bh*NCH + c], w, l);
    }
    ol[j] = o / l;
  }
  __syncthreads();
  float x = 0.f;
  for (int d=0; d<ND; d++) x = fmaf(ol[d], WO[(size_t)d*ND + j], x);
  x += Sv[(size_t)b*ND + j];
  float mu = bsum256(x) * (1.0f/ND);
  float dd = x - mu;
  float var = bsum256(dd*dd) * (1.0f/ND);
  out[(size_t)NBS*ND + (size_t)b*ND + j] = dd * rsqrtf(var + 1e-6f) * g[j] + bta[j];
}

extern "C" void kernel_launch(void* const* d_in, const int* in_sizes, int n_in,
                              void* d_out, int out_size, void* d_ws, size_t ws_size,
                              hipStream_t stream)
{
  const float* h      = (const float*)d_in[0];
  const float* e      = (const float*)d_in[1];
  const float* s      = (const float*)d_in[2];
  const float* sat_wq = (const float*)d_in[3];
  const float* sat_wk = (const float*)d_in[4];
  const float* sat_wv = (const float*)d_in[5];
  const float* sat_wo = (const float*)d_in[6];
  const float* sat_g  = (const float*)d_in[7];
  const float* sat_b  = (const float*)d_in[8];
  const float* rel_wq = (const float*)d_in[9];
  const float* rel_wk = (const float*)d_in[10];
  const float* rel_wv = (const float*)d_in[11];
  const float* rel_wo = (const float*)d_in[12];
  const float* rel_g  = (const float*)d_in[13];
  const float* rel_b  = (const float*)d_in[14];
  float* out = (float*)d_out;

  float* ws = (float*)d_ws;
  ushort_t* hQKV = (ushort_t*)ws;                    // [0,1.5P) bf16 [M][768] q|kh|vh
  ushort_t* h16  = (ushort_t*)(ws + (3*PBUF)/2);     // [1.5P,2P) bf16 h
  ushort_t* eKV  = (ushort_t*)(ws + 2*PBUF);         // [2P,3P) bf16 [M][512] ke|ve
  ushort_t* krv  = (ushort_t*)(ws + 4*PBUF);         // [4P,5P) bf16 [B][4097][512] kr|vr
  ushort_t* hb   = (ushort_t*)(ws + 5*PBUF);         // [5P,5.5P) bf16 h_out
  ushort_t* satO = hb + HSZ;                         // [5.5P,6P) bf16 sat-attn out
  ushort_t* e16  = satO + HSZ;                       // [6P,6.5P) bf16 e
  ushort_t* Wt   = e16 + HSZ;                        // 6 transposed bf16 weights
  float* smalls  = (float*)(Wt + 6*65536);
  ushort_t* ksb = (ushort_t*)smalls;
  ushort_t* vsb = ksb + 2048;
  float* qr  = smalls + 4096;
  float* pO  = smalls + 8192;
  float* pM  = pO + (size_t)NB*NH*NCH*NDK;
  float* pL  = pM + NB*NH*NCH;

  dim3 gb(256);

  // 1. prep: cvt h/e, 6 transposes, 5 s-projections
  prep<<<8328, gb, 0, stream>>>(h, e, h16, e16,
      sat_wq, sat_wk, sat_wv, sat_wo, rel_wk, rel_wv, Wt,
      s, rel_wq, ksb, vsb, qr, krv);

  // 2. fused projections: hQKV + eKV
  gemm_qkve<<<dim3(NBS/128, 10), gb, 0, stream>>>(h16, e16, Wt, hQKV, eKV);

  // 3. satellite attention
  sat_attn4<<<NBS/8, gb, 0, stream>>>(hQKV, eKV, ksb, vsb, satO);

  // 4. oproj + residual + LN -> f32 out + bf16 hb
  oproj_ln<<<NBS/128, gb, 0, stream>>>(satO, Wt + 3*65536, h, sat_g, sat_b, out, hb);

  // 5. relay kr|vr projection
  gemm_krv<<<dim3(NBS/128, 4), gb, 0, stream>>>(hb, Wt + 4*65536, krv);

  // 6. relay attention partials
  rel_part<<<dim3(NB*NH, NCH), gb, 0, stream>>>(qr, krv, pO, pM, pL);

  // 7. relay merge + output + LN
  rel_tail<<<NB, gb, 0, stream>>>(pO, pM, pL, rel_wo, s, rel_g, rel_b, out);
}